// Round 3
// baseline (188.975 us; speedup 1.0000x reference)
//
#include <hip/hip_runtime.h>

#define N_TOT 8192
#define BHALF 4096
#define D 512
#define C 31
#define NKCI 16

typedef float f32x16 __attribute__((ext_vector_type(16)));
typedef __bf16 bf16x8 __attribute__((ext_vector_type(8)));

// ---------------- helpers ----------------
__device__ __forceinline__ uint bf16_rne(uint u) {
  return (u + 0x7fffu + ((u >> 16) & 1u)) >> 16;
}
__device__ __forceinline__ void split2(float x, uint& h, uint& lo) {
  uint u = __float_as_uint(x);
  h = bf16_rne(u);
  float hf = __uint_as_float(h << 16);
  lo = bf16_rne(__float_as_uint(x - hf));
}
__device__ __forceinline__ void gll16(const ushort* g, ushort* s) {
  __builtin_amdgcn_global_load_lds(
      (const __attribute__((address_space(1))) unsigned int*)g,
      (__attribute__((address_space(3))) unsigned int*)s, 16, 0, 0);
}
// 8 global->LDS loads: one fragment-plane (4 rg x 2 ks) for this wave
__device__ __forceinline__ void stage8(const ushort* g0, ushort* lb, int l,
                                       size_t stride_rg, size_t stride_ks) {
  #pragma unroll
  for (int r = 0; r < 8; ++r) {
    int rg = r >> 1, ks = r & 1;
    const ushort* g = g0 + (size_t)rg * stride_rg + (size_t)ks * stride_ks + (size_t)l * 8;
    gll16(g, lb + ((rg * 2 + ks) * 64 + l) * 8);
  }
}

// fused: split into hi/lo bf16 fragment-tiled layout + row sum-of-squares
// layout: [rg32 = row>>5][ks = k>>4][lane = (row&31)+32*((k>>3)&1)][j = k&7] ushort
__global__ __launch_bounds__(256) void k_split(const float* __restrict__ src,
                                               const float* __restrict__ tgt,
                                               ushort* __restrict__ hiG,
                                               ushort* __restrict__ loG,
                                               float* __restrict__ sq) {
  __shared__ float red[4];
  int tid = threadIdx.x;
  int lin = blockIdx.x * 256 + tid;
  int row = lin >> 7;
  int kq = (lin & 127) << 2;
  const float* p = (row < BHALF) ? src + (size_t)row * D : tgt + (size_t)(row - BHALF) * D;
  float4 v = *(const float4*)(p + kq);
  uint h0,l0,h1,l1,h2,l2,h3,l3;
  split2(v.x,h0,l0); split2(v.y,h1,l1); split2(v.z,h2,l2); split2(v.w,h3,l3);
  int rg = row >> 5;
  int ks = kq >> 4;
  int lane = (row & 31) + (((kq >> 3) & 1) << 5);
  int j0 = kq & 7;
  size_t idx = (((size_t)rg * 32 + ks) * 64 + lane) * 8 + j0;
  *(uint2*)(hiG + idx) = make_uint2(h0 | (h1 << 16), h2 | (h3 << 16));
  *(uint2*)(loG + idx) = make_uint2(l0 | (l1 << 16), l2 | (l3 << 16));
  // row sum of squares: threads 0..127 = row, 128..255 = row (same), two rows/block
  float s = v.x*v.x + v.y*v.y + v.z*v.z + v.w*v.w;
  #pragma unroll
  for (int off = 32; off; off >>= 1) s += __shfl_xor(s, off);
  if ((tid & 63) == 0) red[tid >> 6] = s;
  __syncthreads();
  if (tid == 0)   sq[row] = red[0] + red[1];
  if (tid == 128) sq[row] = red[2] + red[3];
}

// coalesced column sums (for closed-form sum(L2)): block = 32 rows, thread = 2 cols
__global__ __launch_bounds__(256) void k_colsum(const float* __restrict__ src,
                                                const float* __restrict__ tgt,
                                                float* __restrict__ m) {
  int r0 = blockIdx.x * 32;
  const float* p = (r0 < BHALF) ? src + (size_t)r0 * D : tgt + (size_t)(r0 - BHALF) * D;
  int c = threadIdx.x * 2;
  float a0 = 0.f, a1 = 0.f;
  for (int r = 0; r < 32; ++r) {
    float2 v = *(const float2*)(p + (size_t)r * D + c);
    a0 += v.x; a1 += v.y;
  }
  atomicAdd(&m[c], a0);
  atomicAdd(&m[c + 1], a1);
}

// t_label column sums + argmax presence
__global__ __launch_bounds__(256) void k_tstats(const float* __restrict__ tl,
                                                float* __restrict__ tsum,
                                                int* __restrict__ pres) {
  __shared__ float ts[C];
  if (threadIdx.x < C) ts[threadIdx.x] = 0.f;
  __syncthreads();
  int base = blockIdx.x * 128 * C;
  for (int idx = threadIdx.x; idx < 128 * C; idx += 256) {
    atomicAdd(&ts[idx % C], tl[base + idx]);
  }
  if (threadIdx.x < 128) {
    int row = blockIdx.x * 128 + threadIdx.x;
    const float* p = tl + (size_t)row * C;
    float best = p[0]; int bi = 0;
    for (int c = 1; c < C; c++) { float v = p[c]; if (v > best) { best = v; bi = c; } }
    pres[bi] = 1;
  }
  __syncthreads();
  if (threadIdx.x < C) atomicAdd(&tsum[threadIdx.x], ts[threadIdx.x]);
}

// single block: bandwidth scalar + class masks/scales
__global__ __launch_bounds__(256) void k_prep(const float* __restrict__ sq,
                                              const float* __restrict__ m,
                                              const int* __restrict__ slab,
                                              const float* __restrict__ tsum,
                                              const int* __restrict__ pres,
                                              float* __restrict__ sval,
                                              float* __restrict__ tscale,
                                              float* __restrict__ scal) {
  __shared__ float red[4];
  __shared__ int cnt[C];
  __shared__ float Ssh, Msh;
  int tid = threadIdx.x;
  if (tid < C) cnt[tid] = 0;
  float s = 0.f;
  for (int i = tid; i < N_TOT; i += 256) s += sq[i];
  #pragma unroll
  for (int off = 32; off; off >>= 1) s += __shfl_xor(s, off);
  if ((tid & 63) == 0) red[tid >> 6] = s;
  __syncthreads();
  if (tid == 0) Ssh = red[0] + red[1] + red[2] + red[3];
  __syncthreads();
  float q = 0.f;
  for (int d = tid; d < D; d += 256) q += m[d] * m[d];
  #pragma unroll
  for (int off = 32; off; off >>= 1) q += __shfl_xor(q, off);
  if ((tid & 63) == 0) red[tid >> 6] = q;
  __syncthreads();
  if (tid == 0) Msh = red[0] + red[1] + red[2] + red[3];
  for (int i = tid; i < BHALF; i += 256) atomicAdd(&cnt[slab[i]], 1);
  __syncthreads();
  if (tid == 0) {
    double S = (double)Ssh, M2 = (double)Msh;
    double sumL2 = 2.0 * (double)N_TOT * S - 2.0 * M2;
    double bw = sumL2 / ((double)N_TOT * (double)N_TOT - (double)N_TOT) / 4.0;
    scal[0] = (float)(-1.0 / bw);
    int len = 0;
    for (int c = 0; c < C; c++) {
      int mk = (cnt[c] > 0 && pres[c] != 0) ? 1 : 0;
      len += mk;
      sval[c] = mk ? (1.0f / (float)cnt[c]) : 0.0f;
      float tv = tsum[c];
      tscale[c] = mk ? (1.0f / (tv == 0.0f ? 1.0f : tv)) : 0.0f;
    }
    scal[1] = (len > 0) ? (1.0f / (float)len) : 0.0f;
  }
}

// signed weight vectors -> split hi/lo, fragment-tiled (K=32 classes)
__global__ __launch_bounds__(256) void k_cvec(const int* __restrict__ slab,
                                              const float* __restrict__ tl,
                                              const float* __restrict__ sval,
                                              const float* __restrict__ tscale,
                                              ushort* __restrict__ cH,
                                              ushort* __restrict__ cL) {
  int row = blockIdx.x * 256 + threadIdx.x;
  float c[32];
  if (row < BHALF) {
    int cls = slab[row];
    float v = sval[cls];
    #pragma unroll
    for (int i = 0; i < 32; ++i) c[i] = (i == cls) ? v : 0.f;
  } else {
    const float* p = tl + (size_t)(row - BHALF) * C;
    #pragma unroll
    for (int i = 0; i < C; ++i) c[i] = -p[i] * tscale[i];
    c[C] = 0.f;
  }
  int rg = row >> 5;
  #pragma unroll
  for (int ks = 0; ks < 2; ++ks)
    #pragma unroll
    for (int hf = 0; hf < 2; ++hf) {
      int lane = (row & 31) + (hf << 5);
      size_t base = (((size_t)rg * 2 + ks) * 64 + lane) * 8;
      uint h[8], lo[8];
      #pragma unroll
      for (int j = 0; j < 8; ++j) split2(c[ks * 16 + hf * 8 + j], h[j], lo[j]);
      *(uint2*)(cH + base)     = make_uint2(h[0]|(h[1]<<16),  h[2]|(h[3]<<16));
      *(uint2*)(cH + base + 4) = make_uint2(h[4]|(h[5]<<16),  h[6]|(h[7]<<16));
      *(uint2*)(cL + base)     = make_uint2(lo[0]|(lo[1]<<16), lo[2]|(lo[3]<<16));
      *(uint2*)(cL + base + 4) = make_uint2(lo[4]|(lo[5]<<16), lo[6]|(lo[7]<<16));
    }
}

// main: double-buffered split-bf16 MFMA distance GEMM + gaussian + weight contraction
__global__ __launch_bounds__(256, 2) void k_main(
    const ushort* __restrict__ hiG, const ushort* __restrict__ loG,
    const ushort* __restrict__ cH, const ushort* __restrict__ cL,
    const float* __restrict__ sq, const float* __restrict__ scal,
    float* __restrict__ out) {
  __shared__ ushort As[2][2][4096];  // [buf][hi/lo][((rg*2+ks)*64+lane)*8]
  __shared__ ushort Bs[2][2][4096];
  __shared__ float sqA[128], sqB[128], red[4];

  int tid = threadIdx.x;
  int l = tid & 63, wid = tid >> 6;

  // bijective XCD swizzle (2080 % 8 == 0): contiguous chunk of 260 per XCD
  int bid = (int)blockIdx.x;
  int swz = (bid & 7) * 260 + (bid >> 3);

  // decode upper-triangle tile index
  int ti = 0, rem = swz;
  for (;;) { int w = 64 - ti; if (rem < w) break; rem -= w; ++ti; }
  int tj = ti + rem;

  if (tid < 128) { sqA[tid] = sq[ti * 128 + tid]; sqB[tid] = sq[tj * 128 + tid]; }
  float nib = scal[0], invlen = scal[1];

  f32x16 zero16;
  #pragma unroll
  for (int k = 0; k < 16; ++k) zero16[k] = 0.f;
  f32x16 acc[2][2];
  acc[0][0] = zero16; acc[0][1] = zero16; acc[1][0] = zero16; acc[1][1] = zero16;

  int wrg = (wid >> 1) * 2;  // wave's local rg32 base (A side)
  int wcg = (wid & 1) * 2;   // wave's local rg32 base (B side)

  // wave staging role: wid0->A_hi, wid1->A_lo, wid2->B_hi, wid3->B_lo
  int plane = wid & 1;
  const ushort* gbase = plane ? loG : hiG;
  const ushort* gcbase = plane ? cL : cH;
  int rgbase = ((wid < 2) ? ti : tj) * 4;

  // prologue: stage K-chunk 0 into buf0
  {
    ushort* lb = (wid < 2) ? As[0][plane] : Bs[0][plane];
    stage8(gbase + (((size_t)rgbase * 32) * 64) * 8, lb, l, 16384, 512);
  }
  __syncthreads();

  for (int kci = 0; kci < NKCI; ++kci) {
    int cur = kci & 1;
    // prefetch next K-chunk (or the weight planes on the last iteration)
    {
      ushort* lb = (wid < 2) ? As[cur ^ 1][plane] : Bs[cur ^ 1][plane];
      if (kci + 1 < NKCI)
        stage8(gbase + (((size_t)rgbase * 32 + (kci + 1) * 2) * 64) * 8, lb, l, 16384, 512);
      else
        stage8(gcbase + ((size_t)rgbase * 2 * 64) * 8, lb, l, 1024, 512);
    }
    bf16x8 aH[2][2], aL[2][2], bH[2][2], bL[2][2];
    #pragma unroll
    for (int rg = 0; rg < 2; ++rg)
      #pragma unroll
      for (int ks = 0; ks < 2; ++ks) {
        int o = (((wrg + rg) * 2 + ks) * 64 + l) * 8;
        aH[rg][ks] = *(const bf16x8*)(As[cur][0] + o);
        aL[rg][ks] = *(const bf16x8*)(As[cur][1] + o);
        int o2 = (((wcg + rg) * 2 + ks) * 64 + l) * 8;
        bH[rg][ks] = *(const bf16x8*)(Bs[cur][0] + o2);
        bL[rg][ks] = *(const bf16x8*)(Bs[cur][1] + o2);
      }
    __builtin_amdgcn_s_setprio(1);
    #pragma unroll
    for (int i = 0; i < 2; ++i)
      #pragma unroll
      for (int j = 0; j < 2; ++j)
        #pragma unroll
        for (int ks = 0; ks < 2; ++ks) {
          acc[i][j] = __builtin_amdgcn_mfma_f32_32x32x16_bf16(aH[i][ks], bH[j][ks], acc[i][j], 0, 0, 0);
          acc[i][j] = __builtin_amdgcn_mfma_f32_32x32x16_bf16(aH[i][ks], bL[j][ks], acc[i][j], 0, 0, 0);
          acc[i][j] = __builtin_amdgcn_mfma_f32_32x32x16_bf16(aL[i][ks], bH[j][ks], acc[i][j], 0, 0, 0);
        }
    __builtin_amdgcn_s_setprio(0);
    __syncthreads();  // drains vmcnt(0): prefetched loads had the whole MFMA phase in flight
  }

  // weight tile W = Ca . Cb^T (K=32 classes) staged in buf0 by the last prefetch
  f32x16 wacc[2][2];
  wacc[0][0] = zero16; wacc[0][1] = zero16; wacc[1][0] = zero16; wacc[1][1] = zero16;
  #pragma unroll
  for (int ks = 0; ks < 2; ++ks) {
    bf16x8 caH[2], caL[2], cbH[2], cbL[2];
    #pragma unroll
    for (int rg = 0; rg < 2; ++rg) {
      int o = (((wrg + rg) * 2 + ks) * 64 + l) * 8;
      caH[rg] = *(const bf16x8*)(As[0][0] + o);
      caL[rg] = *(const bf16x8*)(As[0][1] + o);
      int o2 = (((wcg + rg) * 2 + ks) * 64 + l) * 8;
      cbH[rg] = *(const bf16x8*)(Bs[0][0] + o2);
      cbL[rg] = *(const bf16x8*)(Bs[0][1] + o2);
    }
    #pragma unroll
    for (int i = 0; i < 2; ++i)
      #pragma unroll
      for (int j = 0; j < 2; ++j) {
        wacc[i][j] = __builtin_amdgcn_mfma_f32_32x32x16_bf16(caH[i], cbH[j], wacc[i][j], 0, 0, 0);
        wacc[i][j] = __builtin_amdgcn_mfma_f32_32x32x16_bf16(caH[i], cbL[j], wacc[i][j], 0, 0, 0);
        wacc[i][j] = __builtin_amdgcn_mfma_f32_32x32x16_bf16(caL[i], cbH[j], wacc[i][j], 0, 0, 0);
      }
  }

  // epilogue: L2 -> 5-scale gaussian -> weighted partial sum
  float partial = 0.f;
  int colb = (wid & 1) * 64 + (l & 31);
  int rowb = (wid >> 1) * 64 + 4 * (l >> 5);
  #pragma unroll
  for (int i = 0; i < 2; ++i)
    #pragma unroll
    for (int j = 0; j < 2; ++j) {
      float sb = sqB[colb + j * 32];
      #pragma unroll
      for (int reg = 0; reg < 16; ++reg) {
        int row = rowb + i * 32 + (reg & 3) + 8 * (reg >> 2);
        float l2 = fmaxf(sqA[row] + sb - 2.0f * acc[i][j][reg], 0.f);
        float g = l2 * nib;
        float kern = __expf(g) + __expf(g * 0.5f) + __expf(g * 0.25f)
                   + __expf(g * 0.125f) + __expf(g * 0.0625f);
        partial = fmaf(wacc[i][j][reg], kern, partial);
      }
    }
  #pragma unroll
  for (int off = 32; off; off >>= 1) partial += __shfl_xor(partial, off);
  if (l == 0) red[wid] = partial;
  __syncthreads();
  if (tid == 0) {
    float v = (red[0] + red[1] + red[2] + red[3]) * invlen * ((ti == tj) ? 1.0f : 2.0f);
    atomicAdd(out, v);
  }
}

extern "C" void kernel_launch(void* const* d_in, const int* in_sizes, int n_in,
                              void* d_out, int out_size, void* d_ws, size_t ws_size,
                              hipStream_t stream) {
  const float* src = (const float*)d_in[0];
  const float* tgt = (const float*)d_in[1];
  const int* slab  = (const int*)d_in[2];
  const float* tl  = (const float*)d_in[3];
  float* out = (float*)d_out;

  ushort* hiG = (ushort*)d_ws;           // 8192*512 ushorts
  ushort* loG = hiG + 4194304;
  ushort* cH  = loG + 4194304;           // 8192*32
  ushort* cL  = cH + 262144;
  float* fb   = (float*)(cL + 262144);
  float* sq     = fb;            // 8192
  float* m      = fb + 8192;     // 512
  float* tsum   = fb + 8704;     // 32
  int*   pres   = (int*)(fb + 8736);  // 32
  float* sval   = fb + 8768;     // 32
  float* tscale = fb + 8800;     // 32
  float* scal   = fb + 8832;     // 2

  hipMemsetAsync(out, 0, sizeof(float), stream);
  hipMemsetAsync(m, 0, 576 * sizeof(float), stream);

  hipLaunchKernelGGL(k_split,  dim3(4096), dim3(256), 0, stream, src, tgt, hiG, loG, sq);
  hipLaunchKernelGGL(k_colsum, dim3(256),  dim3(256), 0, stream, src, tgt, m);
  hipLaunchKernelGGL(k_tstats, dim3(32),   dim3(256), 0, stream, tl, tsum, pres);
  hipLaunchKernelGGL(k_prep,   dim3(1),    dim3(256), 0, stream, sq, m, slab, tsum, pres, sval, tscale, scal);
  hipLaunchKernelGGL(k_cvec,   dim3(32),   dim3(256), 0, stream, slab, tl, sval, tscale, cH, cL);
  hipLaunchKernelGGL(k_main,   dim3(2080), dim3(256), 0, stream, hiG, loG, cH, cL, sq, scal, out);
}

// Round 4
// 140.560 us; speedup vs baseline: 1.3444x; 1.3444x over previous
//
#include <hip/hip_runtime.h>

#define N_TOT 8192
#define BHALF 4096
#define D 512
#define C 31
#define NKCI 8   // K-chunks of 64

typedef float f32x16 __attribute__((ext_vector_type(16)));
typedef __bf16 bf16x8 __attribute__((ext_vector_type(8)));

// ---------------- helpers ----------------
__device__ __forceinline__ uint bf16_rne(uint u) {
  return (u + 0x7fffu + ((u >> 16) & 1u)) >> 16;
}
__device__ __forceinline__ void split2(float x, uint& h, uint& lo) {
  uint u = __float_as_uint(x);
  h = bf16_rne(u);
  float hf = __uint_as_float(h << 16);
  lo = bf16_rne(__float_as_uint(x - hf));
}
__device__ __forceinline__ void gll16(const ushort* g, ushort* s) {
  __builtin_amdgcn_global_load_lds(
      (const __attribute__((address_space(1))) unsigned int*)g,
      (__attribute__((address_space(3))) unsigned int*)s, 16, 0, 0);
}

// fused: split into hi bf16 fragment-tiled layout + row sum-of-squares
// layout: [rg32 = row>>5][ksg = k>>4][lane = (row&31)+32*((k>>3)&1)][j = k&7] ushort
__global__ __launch_bounds__(256) void k_split(const float* __restrict__ src,
                                               const float* __restrict__ tgt,
                                               ushort* __restrict__ hiG,
                                               float* __restrict__ sq) {
  __shared__ float red[4];
  int tid = threadIdx.x;
  int lin = blockIdx.x * 256 + tid;
  int row = lin >> 7;
  int kq = (lin & 127) << 2;
  const float* p = (row < BHALF) ? src + (size_t)row * D : tgt + (size_t)(row - BHALF) * D;
  float4 v = *(const float4*)(p + kq);
  uint h0 = bf16_rne(__float_as_uint(v.x));
  uint h1 = bf16_rne(__float_as_uint(v.y));
  uint h2 = bf16_rne(__float_as_uint(v.z));
  uint h3 = bf16_rne(__float_as_uint(v.w));
  int rg = row >> 5;
  int ksg = kq >> 4;
  int lane = (row & 31) + (((kq >> 3) & 1) << 5);
  int j0 = kq & 7;
  size_t idx = (((size_t)rg * 32 + ksg) * 64 + lane) * 8 + j0;
  *(uint2*)(hiG + idx) = make_uint2(h0 | (h1 << 16), h2 | (h3 << 16));
  float s = v.x*v.x + v.y*v.y + v.z*v.z + v.w*v.w;
  #pragma unroll
  for (int off = 32; off; off >>= 1) s += __shfl_xor(s, off);
  if ((tid & 63) == 0) red[tid >> 6] = s;
  __syncthreads();
  if (tid == 0)   sq[row] = red[0] + red[1];
  if (tid == 128) sq[row] = red[2] + red[3];
}

// coalesced column sums (for closed-form sum(L2))
__global__ __launch_bounds__(256) void k_colsum(const float* __restrict__ src,
                                                const float* __restrict__ tgt,
                                                float* __restrict__ m) {
  int r0 = blockIdx.x * 32;
  const float* p = (r0 < BHALF) ? src + (size_t)r0 * D : tgt + (size_t)(r0 - BHALF) * D;
  int c = threadIdx.x * 2;
  float a0 = 0.f, a1 = 0.f;
  for (int r = 0; r < 32; ++r) {
    float2 v = *(const float2*)(p + (size_t)r * D + c);
    a0 += v.x; a1 += v.y;
  }
  atomicAdd(&m[c], a0);
  atomicAdd(&m[c + 1], a1);
}

// t_label column sums + argmax presence
__global__ __launch_bounds__(256) void k_tstats(const float* __restrict__ tl,
                                                float* __restrict__ tsum,
                                                int* __restrict__ pres) {
  __shared__ float ts[C];
  if (threadIdx.x < C) ts[threadIdx.x] = 0.f;
  __syncthreads();
  int base = blockIdx.x * 128 * C;
  for (int idx = threadIdx.x; idx < 128 * C; idx += 256) {
    atomicAdd(&ts[idx % C], tl[base + idx]);
  }
  if (threadIdx.x < 128) {
    int row = blockIdx.x * 128 + threadIdx.x;
    const float* p = tl + (size_t)row * C;
    float best = p[0]; int bi = 0;
    for (int c = 1; c < C; c++) { float v = p[c]; if (v > best) { best = v; bi = c; } }
    pres[bi] = 1;
  }
  __syncthreads();
  if (threadIdx.x < C) atomicAdd(&tsum[threadIdx.x], ts[threadIdx.x]);
}

// single block: bandwidth scalar + class masks/scales
__global__ __launch_bounds__(256) void k_prep(const float* __restrict__ sq,
                                              const float* __restrict__ m,
                                              const int* __restrict__ slab,
                                              const float* __restrict__ tsum,
                                              const int* __restrict__ pres,
                                              float* __restrict__ sval,
                                              float* __restrict__ tscale,
                                              float* __restrict__ scal) {
  __shared__ float red[4];
  __shared__ int cnt[C];
  __shared__ float Ssh, Msh;
  int tid = threadIdx.x;
  if (tid < C) cnt[tid] = 0;
  float s = 0.f;
  for (int i = tid; i < N_TOT; i += 256) s += sq[i];
  #pragma unroll
  for (int off = 32; off; off >>= 1) s += __shfl_xor(s, off);
  if ((tid & 63) == 0) red[tid >> 6] = s;
  __syncthreads();
  if (tid == 0) Ssh = red[0] + red[1] + red[2] + red[3];
  __syncthreads();
  float q = 0.f;
  for (int d = tid; d < D; d += 256) q += m[d] * m[d];
  #pragma unroll
  for (int off = 32; off; off >>= 1) q += __shfl_xor(q, off);
  if ((tid & 63) == 0) red[tid >> 6] = q;
  __syncthreads();
  if (tid == 0) Msh = red[0] + red[1] + red[2] + red[3];
  for (int i = tid; i < BHALF; i += 256) atomicAdd(&cnt[slab[i]], 1);
  __syncthreads();
  if (tid == 0) {
    double S = (double)Ssh, M2 = (double)Msh;
    double sumL2 = 2.0 * (double)N_TOT * S - 2.0 * M2;
    double bw = sumL2 / ((double)N_TOT * (double)N_TOT - (double)N_TOT) / 4.0;
    scal[0] = (float)(-1.0 / bw);
    int len = 0;
    for (int c = 0; c < C; c++) {
      int mk = (cnt[c] > 0 && pres[c] != 0) ? 1 : 0;
      len += mk;
      sval[c] = mk ? (1.0f / (float)cnt[c]) : 0.0f;
      float tv = tsum[c];
      tscale[c] = mk ? (1.0f / (tv == 0.0f ? 1.0f : tv)) : 0.0f;
    }
    scal[1] = (len > 0) ? (1.0f / (float)len) : 0.0f;
  }
}

// signed weight vectors -> split hi/lo, fragment-tiled (K=32 classes)
// layout: [rg32][ks = cls>>4][lane = (row&31)+32*((cls>>3)&1)][j = cls&7]
__global__ __launch_bounds__(256) void k_cvec(const int* __restrict__ slab,
                                              const float* __restrict__ tl,
                                              const float* __restrict__ sval,
                                              const float* __restrict__ tscale,
                                              ushort* __restrict__ cH,
                                              ushort* __restrict__ cL) {
  int row = blockIdx.x * 256 + threadIdx.x;
  float c[32];
  if (row < BHALF) {
    int cls = slab[row];
    float v = sval[cls];
    #pragma unroll
    for (int i = 0; i < 32; ++i) c[i] = (i == cls) ? v : 0.f;
  } else {
    const float* p = tl + (size_t)(row - BHALF) * C;
    #pragma unroll
    for (int i = 0; i < C; ++i) c[i] = -p[i] * tscale[i];
    c[C] = 0.f;
  }
  int rg = row >> 5;
  #pragma unroll
  for (int ks = 0; ks < 2; ++ks)
    #pragma unroll
    for (int hf = 0; hf < 2; ++hf) {
      int lane = (row & 31) + (hf << 5);
      size_t base = (((size_t)rg * 2 + ks) * 64 + lane) * 8;
      uint h[8], lo[8];
      #pragma unroll
      for (int j = 0; j < 8; ++j) split2(c[ks * 16 + hf * 8 + j], h[j], lo[j]);
      *(uint2*)(cH + base)     = make_uint2(h[0]|(h[1]<<16),  h[2]|(h[3]<<16));
      *(uint2*)(cH + base + 4) = make_uint2(h[4]|(h[5]<<16),  h[6]|(h[7]<<16));
      *(uint2*)(cL + base)     = make_uint2(lo[0]|(lo[1]<<16), lo[2]|(lo[3]<<16));
      *(uint2*)(cL + base + 4) = make_uint2(lo[4]|(lo[5]<<16), lo[6]|(lo[7]<<16));
    }
}

// main: hi-only bf16 MFMA distance GEMM (BK=64 dbuf) + gaussian + 3-plane weight tile
__global__ __launch_bounds__(256, 2) void k_main(
    const ushort* __restrict__ hiG,
    const ushort* __restrict__ cH, const ushort* __restrict__ cL,
    const float* __restrict__ sq, const float* __restrict__ scal,
    float* __restrict__ out) {
  __shared__ ushort As[2][8192];  // [buf][((rgl*4+ksl)*64+lane)*8], BK=64
  __shared__ ushort Bs[2][8192];
  __shared__ float sqA[128], sqB[128], red[4];

  int tid = threadIdx.x;
  int l = tid & 63, wid = tid >> 6;

  // bijective XCD swizzle (2080 % 8 == 0)
  int bid = (int)blockIdx.x;
  int swz = (bid & 7) * 260 + (bid >> 3);

  // decode upper-triangle tile index
  int ti = 0, rem = swz;
  for (;;) { int w = 64 - ti; if (rem < w) break; rem -= w; ++ti; }
  int tj = ti + rem;

  if (tid < 128) { sqA[tid] = sq[ti * 128 + tid]; sqB[tid] = sq[tj * 128 + tid]; }
  float nib = scal[0], invlen = scal[1];

  f32x16 zero16;
  #pragma unroll
  for (int k = 0; k < 16; ++k) zero16[k] = 0.f;
  f32x16 acc[2][2];
  acc[0][0] = zero16; acc[0][1] = zero16; acc[1][0] = zero16; acc[1][1] = zero16;

  int wrg = (wid >> 1) * 2;  // wave's A-side local rg base
  int wcg = (wid & 1) * 2;   // wave's B-side local rg base

  // main staging role: wid0/1 -> A (rgl {0,1}/{2,3}), wid2/3 -> B
  int rgbase_m = ((wid < 2) ? ti : tj) * 4;
  int rg_off = (wid & 1) * 2;

  // prologue: stage K-chunk 0 into buf0
  {
    ushort* lb = (wid < 2) ? As[0] : Bs[0];
    #pragma unroll
    for (int r = 0; r < 8; ++r) {
      int rgl = rg_off + (r >> 2), ksl = r & 3;
      const ushort* g = hiG + (((size_t)(rgbase_m + rgl) * 32 + ksl) * 64 + l) * 8;
      gll16(g, lb + ((rgl * 4 + ksl) * 64 + l) * 8);
    }
  }
  __syncthreads();

  for (int kci = 0; kci < NKCI; ++kci) {
    int cur = kci & 1;
    if (kci + 1 < NKCI) {
      ushort* lb = (wid < 2) ? As[cur ^ 1] : Bs[cur ^ 1];
      #pragma unroll
      for (int r = 0; r < 8; ++r) {
        int rgl = rg_off + (r >> 2), ksl = r & 3;
        const ushort* g = hiG + (((size_t)(rgbase_m + rgl) * 32 + (kci + 1) * 4 + ksl) * 64 + l) * 8;
        gll16(g, lb + ((rgl * 4 + ksl) * 64 + l) * 8);
      }
    }
    __builtin_amdgcn_s_setprio(1);
    #pragma unroll
    for (int ksl = 0; ksl < 4; ++ksl) {
      bf16x8 a0 = *(const bf16x8*)(As[cur] + (((wrg + 0) * 4 + ksl) * 64 + l) * 8);
      bf16x8 a1 = *(const bf16x8*)(As[cur] + (((wrg + 1) * 4 + ksl) * 64 + l) * 8);
      bf16x8 b0 = *(const bf16x8*)(Bs[cur] + (((wcg + 0) * 4 + ksl) * 64 + l) * 8);
      bf16x8 b1 = *(const bf16x8*)(Bs[cur] + (((wcg + 1) * 4 + ksl) * 64 + l) * 8);
      acc[0][0] = __builtin_amdgcn_mfma_f32_32x32x16_bf16(a0, b0, acc[0][0], 0, 0, 0);
      acc[0][1] = __builtin_amdgcn_mfma_f32_32x32x16_bf16(a0, b1, acc[0][1], 0, 0, 0);
      acc[1][0] = __builtin_amdgcn_mfma_f32_32x32x16_bf16(a1, b0, acc[1][0], 0, 0, 0);
      acc[1][1] = __builtin_amdgcn_mfma_f32_32x32x16_bf16(a1, b1, acc[1][1], 0, 0, 0);
    }
    __builtin_amdgcn_s_setprio(0);
    __syncthreads();
  }

  // stage weight planes: As[0]=caH, As[1]=caL, Bs[0]=cbH, Bs[1]=cbL
  {
    const ushort* gc = (wid & 1) ? cL : cH;
    ushort* lb = (wid < 2) ? As[wid & 1] : Bs[wid & 1];
    int rgbase = ((wid < 2) ? ti : tj) * 4;
    #pragma unroll
    for (int r = 0; r < 8; ++r) {
      int rg = r >> 1, ks = r & 1;
      const ushort* g = gc + (((size_t)(rgbase + rg) * 2 + ks) * 64 + l) * 8;
      gll16(g, lb + ((rg * 2 + ks) * 64 + l) * 8);
    }
  }
  __syncthreads();

  // epilogue: per-quadrant 3-plane weight MFMA, gaussian, contraction
  float partial = 0.f;
  int colb = (wid & 1) * 64 + (l & 31);
  int rowb = (wid >> 1) * 64 + 4 * (l >> 5);
  #pragma unroll
  for (int i = 0; i < 2; ++i) {
    bf16x8 caH0 = *(const bf16x8*)(As[0] + (((wrg + i) * 2 + 0) * 64 + l) * 8);
    bf16x8 caH1 = *(const bf16x8*)(As[0] + (((wrg + i) * 2 + 1) * 64 + l) * 8);
    bf16x8 caL0 = *(const bf16x8*)(As[1] + (((wrg + i) * 2 + 0) * 64 + l) * 8);
    bf16x8 caL1 = *(const bf16x8*)(As[1] + (((wrg + i) * 2 + 1) * 64 + l) * 8);
    #pragma unroll
    for (int j = 0; j < 2; ++j) {
      bf16x8 cbH0 = *(const bf16x8*)(Bs[0] + (((wcg + j) * 2 + 0) * 64 + l) * 8);
      bf16x8 cbH1 = *(const bf16x8*)(Bs[0] + (((wcg + j) * 2 + 1) * 64 + l) * 8);
      bf16x8 cbL0 = *(const bf16x8*)(Bs[1] + (((wcg + j) * 2 + 0) * 64 + l) * 8);
      bf16x8 cbL1 = *(const bf16x8*)(Bs[1] + (((wcg + j) * 2 + 1) * 64 + l) * 8);
      f32x16 w = zero16;
      w = __builtin_amdgcn_mfma_f32_32x32x16_bf16(caH0, cbH0, w, 0, 0, 0);
      w = __builtin_amdgcn_mfma_f32_32x32x16_bf16(caH1, cbH1, w, 0, 0, 0);
      w = __builtin_amdgcn_mfma_f32_32x32x16_bf16(caH0, cbL0, w, 0, 0, 0);
      w = __builtin_amdgcn_mfma_f32_32x32x16_bf16(caH1, cbL1, w, 0, 0, 0);
      w = __builtin_amdgcn_mfma_f32_32x32x16_bf16(caL0, cbH0, w, 0, 0, 0);
      w = __builtin_amdgcn_mfma_f32_32x32x16_bf16(caL1, cbH1, w, 0, 0, 0);
      float sb = sqB[colb + j * 32];
      #pragma unroll
      for (int reg = 0; reg < 16; ++reg) {
        int row = rowb + i * 32 + (reg & 3) + 8 * (reg >> 2);
        float l2 = fmaxf(sqA[row] + sb - 2.0f * acc[i][j][reg], 0.f);
        float g = l2 * nib;
        float kern = __expf(g) + __expf(g * 0.5f) + __expf(g * 0.25f)
                   + __expf(g * 0.125f) + __expf(g * 0.0625f);
        partial = fmaf(w[reg], kern, partial);
      }
    }
  }
  #pragma unroll
  for (int off = 32; off; off >>= 1) partial += __shfl_xor(partial, off);
  if (l == 0) red[wid] = partial;
  __syncthreads();
  if (tid == 0) {
    float v = (red[0] + red[1] + red[2] + red[3]) * invlen * ((ti == tj) ? 1.0f : 2.0f);
    atomicAdd(out, v);
  }
}

extern "C" void kernel_launch(void* const* d_in, const int* in_sizes, int n_in,
                              void* d_out, int out_size, void* d_ws, size_t ws_size,
                              hipStream_t stream) {
  const float* src = (const float*)d_in[0];
  const float* tgt = (const float*)d_in[1];
  const int* slab  = (const int*)d_in[2];
  const float* tl  = (const float*)d_in[3];
  float* out = (float*)d_out;

  ushort* hiG = (ushort*)d_ws;           // 8192*512 ushorts
  ushort* cH  = hiG + 4194304;           // 8192*32
  ushort* cL  = cH + 262144;
  float* fb   = (float*)(cL + 262144);
  float* sq     = fb;            // 8192
  float* m      = fb + 8192;     // 512
  float* tsum   = fb + 8704;     // 32
  int*   pres   = (int*)(fb + 8736);  // 32
  float* sval   = fb + 8768;     // 32
  float* tscale = fb + 8800;     // 32
  float* scal   = fb + 8832;     // 2

  hipMemsetAsync(out, 0, sizeof(float), stream);
  hipMemsetAsync(m, 0, 576 * sizeof(float), stream);

  hipLaunchKernelGGL(k_split,  dim3(4096), dim3(256), 0, stream, src, tgt, hiG, sq);
  hipLaunchKernelGGL(k_colsum, dim3(256),  dim3(256), 0, stream, src, tgt, m);
  hipLaunchKernelGGL(k_tstats, dim3(32),   dim3(256), 0, stream, tl, tsum, pres);
  hipLaunchKernelGGL(k_prep,   dim3(1),    dim3(256), 0, stream, sq, m, slab, tsum, pres, sval, tscale, scal);
  hipLaunchKernelGGL(k_cvec,   dim3(32),   dim3(256), 0, stream, slab, tl, sval, tscale, cH, cL);
  hipLaunchKernelGGL(k_main,   dim3(2080), dim3(256), 0, stream, hiG, cH, cL, sq, scal, out);
}

// Round 6
// 109.579 us; speedup vs baseline: 1.7245x; 1.2827x over previous
//
#include <hip/hip_runtime.h>

#define N_TOT 8192
#define BHALF 4096
#define D 512
#define C 31
#define NKCI 8   // K-chunks of 64

typedef float f32x16 __attribute__((ext_vector_type(16)));
typedef __bf16 bf16x8 __attribute__((ext_vector_type(8)));

// ---------------- helpers ----------------
__device__ __forceinline__ uint bf16_rne(uint u) {
  return (u + 0x7fffu + ((u >> 16) & 1u)) >> 16;
}
__device__ __forceinline__ void split2(float x, uint& h, uint& lo) {
  uint u = __float_as_uint(x);
  h = bf16_rne(u);
  float hf = __uint_as_float(h << 16);
  lo = bf16_rne(__float_as_uint(x - hf));
}
__device__ __forceinline__ void gll16(const ushort* g, ushort* s) {
  __builtin_amdgcn_global_load_lds(
      (const __attribute__((address_space(1))) unsigned int*)g,
      (__attribute__((address_space(3))) unsigned int*)s, 16, 0, 0);
}

// fused: bf16-split (fragment-tiled, wave-contiguous writes) + row sq + col sums
// hiG[((rg*32+ksg)*64 + l)*8 + j] = bf16(x[rg*32+(l&31)][ksg*16+(l>>5)*8+j])
__global__ __launch_bounds__(256) void k_split(const float* __restrict__ src,
                                               const float* __restrict__ tgt,
                                               ushort* __restrict__ hiG,
                                               float* __restrict__ sq,
                                               float* __restrict__ m) {
  __shared__ float lsq[4][32];
  __shared__ float lcol[64];
  int tid = threadIdx.x, l = tid & 63, wid = tid >> 6;
  int rg = blockIdx.x >> 3;    // 0..255
  int kb = blockIdx.x & 7;     // 0..7
  int ksg = kb * 4 + wid;      // 0..31
  int row = rg * 32 + (l & 31);
  int k0 = ksg * 16 + (l >> 5) * 8;
  const float* p = (row < BHALF) ? src + (size_t)row * D : tgt + (size_t)(row - BHALF) * D;
  float4 v0 = *(const float4*)(p + k0);
  float4 v1 = *(const float4*)(p + k0 + 4);
  float x[8] = {v0.x, v0.y, v0.z, v0.w, v1.x, v1.y, v1.z, v1.w};
  uint h[8];
  #pragma unroll
  for (int j = 0; j < 8; ++j) h[j] = bf16_rne(__float_as_uint(x[j]));
  uint4 o = make_uint4(h[0] | (h[1] << 16), h[2] | (h[3] << 16),
                       h[4] | (h[5] << 16), h[6] | (h[7] << 16));
  *(uint4*)(hiG + (((size_t)rg * 32 + ksg) * 64 + l) * 8) = o;
  // row sum-of-squares partial (this wave covers 16 cols of each of 32 rows)
  float s = 0.f;
  #pragma unroll
  for (int j = 0; j < 8; ++j) s = fmaf(x[j], x[j], s);
  s += __shfl_xor(s, 32);
  if (l < 32) lsq[wid][l] = s;
  // column partials: butterfly-reduce over the 32-row dim (lane bits 0..4)
  float c[8];
  #pragma unroll
  for (int j = 0; j < 8; ++j) c[j] = x[j];
  #pragma unroll
  for (int off = 1; off <= 16; off <<= 1)
    #pragma unroll
    for (int j = 0; j < 8; ++j) c[j] += __shfl_xor(c[j], off);
  if ((l & 31) == 0) {
    #pragma unroll
    for (int j = 0; j < 8; ++j) lcol[wid * 16 + (l >> 5) * 8 + j] = c[j];
  }
  __syncthreads();
  if (tid < 32) {
    float t = lsq[0][tid] + lsq[1][tid] + lsq[2][tid] + lsq[3][tid];
    atomicAdd(&sq[rg * 32 + tid], t);
  } else if (tid >= 64 && tid < 128) {
    int cc = tid - 64;
    atomicAdd(&m[kb * 64 + cc], lcol[cc]);
  }
}

// t_label column sums + argmax presence
__global__ __launch_bounds__(256) void k_tstats(const float* __restrict__ tl,
                                                float* __restrict__ tsum,
                                                int* __restrict__ pres) {
  __shared__ float ts[C];
  if (threadIdx.x < C) ts[threadIdx.x] = 0.f;
  __syncthreads();
  int base = blockIdx.x * 128 * C;
  for (int idx = threadIdx.x; idx < 128 * C; idx += 256) {
    atomicAdd(&ts[idx % C], tl[base + idx]);
  }
  if (threadIdx.x < 128) {
    int row = blockIdx.x * 128 + threadIdx.x;
    const float* p = tl + (size_t)row * C;
    float best = p[0]; int bi = 0;
    for (int c = 1; c < C; c++) { float v = p[c]; if (v > best) { best = v; bi = c; } }
    pres[bi] = 1;
  }
  __syncthreads();
  if (threadIdx.x < C) atomicAdd(&tsum[threadIdx.x], ts[threadIdx.x]);
}

// single block: bandwidth scalar + class masks/scales
__global__ __launch_bounds__(256) void k_prep(const float* __restrict__ sq,
                                              const float* __restrict__ m,
                                              const int* __restrict__ slab,
                                              const float* __restrict__ tsum,
                                              const int* __restrict__ pres,
                                              float* __restrict__ sval,
                                              float* __restrict__ tscale,
                                              float* __restrict__ scal) {
  __shared__ float red[4];
  __shared__ int cnt[C];
  __shared__ float Ssh, Msh;
  int tid = threadIdx.x;
  if (tid < C) cnt[tid] = 0;
  float s = 0.f;
  for (int i = tid; i < N_TOT; i += 256) s += sq[i];
  #pragma unroll
  for (int off = 32; off; off >>= 1) s += __shfl_xor(s, off);
  if ((tid & 63) == 0) red[tid >> 6] = s;
  __syncthreads();
  if (tid == 0) Ssh = red[0] + red[1] + red[2] + red[3];
  __syncthreads();
  float q = 0.f;
  for (int d = tid; d < D; d += 256) q += m[d] * m[d];
  #pragma unroll
  for (int off = 32; off; off >>= 1) q += __shfl_xor(q, off);
  if ((tid & 63) == 0) red[tid >> 6] = q;
  __syncthreads();
  if (tid == 0) Msh = red[0] + red[1] + red[2] + red[3];
  for (int i = tid; i < BHALF; i += 256) atomicAdd(&cnt[slab[i]], 1);
  __syncthreads();
  if (tid == 0) {
    double S = (double)Ssh, M2 = (double)Msh;
    double sumL2 = 2.0 * (double)N_TOT * S - 2.0 * M2;
    double bw = sumL2 / ((double)N_TOT * (double)N_TOT - (double)N_TOT) / 4.0;
    // e = 2^(L2 * scal0) = exp(-L2/(16*bw)); 4 squarings give the other scales
    scal[0] = (float)(-1.4426950408889634 / (16.0 * bw));
    int len = 0;
    for (int c = 0; c < C; c++) {
      int mk = (cnt[c] > 0 && pres[c] != 0) ? 1 : 0;
      len += mk;
      sval[c] = mk ? (1.0f / (float)cnt[c]) : 0.0f;
      float tv = tsum[c];
      tscale[c] = mk ? (1.0f / (tv == 0.0f ? 1.0f : tv)) : 0.0f;
    }
    scal[1] = (len > 0) ? (1.0f / (float)len) : 0.0f;
  }
}

// signed weight vectors -> split hi/lo, fragment-tiled (K=32 classes)
__global__ __launch_bounds__(256) void k_cvec(const int* __restrict__ slab,
                                              const float* __restrict__ tl,
                                              const float* __restrict__ sval,
                                              const float* __restrict__ tscale,
                                              ushort* __restrict__ cH,
                                              ushort* __restrict__ cL) {
  int row = blockIdx.x * 256 + threadIdx.x;
  float c[32];
  if (row < BHALF) {
    int cls = slab[row];
    float v = sval[cls];
    #pragma unroll
    for (int i = 0; i < 32; ++i) c[i] = (i == cls) ? v : 0.f;
  } else {
    const float* p = tl + (size_t)(row - BHALF) * C;
    #pragma unroll
    for (int i = 0; i < C; ++i) c[i] = -p[i] * tscale[i];
    c[C] = 0.f;
  }
  int rg = row >> 5;
  #pragma unroll
  for (int ks = 0; ks < 2; ++ks)
    #pragma unroll
    for (int hf = 0; hf < 2; ++hf) {
      int lane = (row & 31) + (hf << 5);
      size_t base = (((size_t)rg * 2 + ks) * 64 + lane) * 8;
      uint h[8], lo[8];
      #pragma unroll
      for (int j = 0; j < 8; ++j) split2(c[ks * 16 + hf * 8 + j], h[j], lo[j]);
      *(uint2*)(cH + base)     = make_uint2(h[0]|(h[1]<<16),  h[2]|(h[3]<<16));
      *(uint2*)(cH + base + 4) = make_uint2(h[4]|(h[5]<<16),  h[6]|(h[7]<<16));
      *(uint2*)(cL + base)     = make_uint2(lo[0]|(lo[1]<<16), lo[2]|(lo[3]<<16));
      *(uint2*)(cL + base + 4) = make_uint2(lo[4]|(lo[5]<<16), lo[6]|(lo[7]<<16));
    }
}

// main: hi-only bf16 MFMA GEMM, single-buffer BK=64 (4 blocks/CU) + folded-exp epilogue
__global__ __launch_bounds__(256, 4) void k_main(
    const ushort* __restrict__ hiG,
    const ushort* __restrict__ cH, const ushort* __restrict__ cL,
    const float* __restrict__ sq, const float* __restrict__ scal,
    float* __restrict__ out) {
  __shared__ ushort As[8192];  // [((rgl*4+ksl)*64+lane)*8], BK=64 (16KB)
  __shared__ ushort Bs[8192];
  __shared__ float sqA[128], sqB[128], red[4];

  int tid = threadIdx.x;
  int l = tid & 63, wid = tid >> 6;

  // bijective XCD swizzle (2080 % 8 == 0)
  int bid = (int)blockIdx.x;
  int swz = (bid & 7) * 260 + (bid >> 3);

  // decode upper-triangle tile index
  int ti = 0, rem = swz;
  for (;;) { int w = 64 - ti; if (rem < w) break; rem -= w; ++ti; }
  int tj = ti + rem;

  if (tid < 128) { sqA[tid] = sq[ti * 128 + tid]; sqB[tid] = sq[tj * 128 + tid]; }
  float nib = scal[0], invlen = scal[1];

  f32x16 zero16;
  #pragma unroll
  for (int k = 0; k < 16; ++k) zero16[k] = 0.f;
  f32x16 acc[2][2];
  acc[0][0] = zero16; acc[0][1] = zero16; acc[1][0] = zero16; acc[1][1] = zero16;

  int wrg = (wid >> 1) * 2;  // wave's A-side local rg base
  int wcg = (wid & 1) * 2;   // wave's B-side local rg base

  // staging role: wid0/1 -> A (rgl {0,1}/{2,3}), wid2/3 -> B
  int rgbase_m = ((wid < 2) ? ti : tj) * 4;
  int rg_off = (wid & 1) * 2;
  ushort* lb_m = (wid < 2) ? As : Bs;

  for (int kci = 0; kci < NKCI; ++kci) {
    #pragma unroll
    for (int r = 0; r < 8; ++r) {
      int rgl = rg_off + (r >> 2), ksl = r & 3;
      const ushort* g = hiG + (((size_t)(rgbase_m + rgl) * 32 + kci * 4 + ksl) * 64 + l) * 8;
      gll16(g, lb_m + ((rgl * 4 + ksl) * 64 + l) * 8);
    }
    __syncthreads();
    __builtin_amdgcn_s_setprio(1);
    #pragma unroll
    for (int ksl = 0; ksl < 4; ++ksl) {
      bf16x8 a0 = *(const bf16x8*)(As + (((wrg + 0) * 4 + ksl) * 64 + l) * 8);
      bf16x8 a1 = *(const bf16x8*)(As + (((wrg + 1) * 4 + ksl) * 64 + l) * 8);
      bf16x8 b0 = *(const bf16x8*)(Bs + (((wcg + 0) * 4 + ksl) * 64 + l) * 8);
      bf16x8 b1 = *(const bf16x8*)(Bs + (((wcg + 1) * 4 + ksl) * 64 + l) * 8);
      acc[0][0] = __builtin_amdgcn_mfma_f32_32x32x16_bf16(a0, b0, acc[0][0], 0, 0, 0);
      acc[0][1] = __builtin_amdgcn_mfma_f32_32x32x16_bf16(a0, b1, acc[0][1], 0, 0, 0);
      acc[1][0] = __builtin_amdgcn_mfma_f32_32x32x16_bf16(a1, b0, acc[1][0], 0, 0, 0);
      acc[1][1] = __builtin_amdgcn_mfma_f32_32x32x16_bf16(a1, b1, acc[1][1], 0, 0, 0);
    }
    __builtin_amdgcn_s_setprio(0);
    __syncthreads();
  }

  // stage weight planes: As = [caH | caL], Bs = [cbH | cbL] (4096 ushorts each)
  {
    const ushort* gc = (wid & 1) ? cL : cH;
    ushort* lb = ((wid < 2) ? As : Bs) + (wid & 1) * 4096;
    int rgbase = ((wid < 2) ? ti : tj) * 4;
    #pragma unroll
    for (int r = 0; r < 8; ++r) {
      int rg = r >> 1, ks = r & 1;
      const ushort* g = gc + (((size_t)(rgbase + rg) * 2 + ks) * 64 + l) * 8;
      gll16(g, lb + ((rg * 2 + ks) * 64 + l) * 8);
    }
  }
  __syncthreads();

  // epilogue: per-quadrant 3-plane weight MFMA, folded-exp gaussian, contraction
  float partial = 0.f;
  int colb = (wid & 1) * 64 + (l & 31);
  int rowb = (wid >> 1) * 64 + 4 * (l >> 5);
  #pragma unroll
  for (int i = 0; i < 2; ++i) {
    bf16x8 caH0 = *(const bf16x8*)(As + (((wrg + i) * 2 + 0) * 64 + l) * 8);
    bf16x8 caH1 = *(const bf16x8*)(As + (((wrg + i) * 2 + 1) * 64 + l) * 8);
    bf16x8 caL0 = *(const bf16x8*)(As + 4096 + (((wrg + i) * 2 + 0) * 64 + l) * 8);
    bf16x8 caL1 = *(const bf16x8*)(As + 4096 + (((wrg + i) * 2 + 1) * 64 + l) * 8);
    #pragma unroll
    for (int j = 0; j < 2; ++j) {
      bf16x8 cbH0 = *(const bf16x8*)(Bs + (((wcg + j) * 2 + 0) * 64 + l) * 8);
      bf16x8 cbH1 = *(const bf16x8*)(Bs + (((wcg + j) * 2 + 1) * 64 + l) * 8);
      bf16x8 cbL0 = *(const bf16x8*)(Bs + 4096 + (((wcg + j) * 2 + 0) * 64 + l) * 8);
      bf16x8 cbL1 = *(const bf16x8*)(Bs + 4096 + (((wcg + j) * 2 + 1) * 64 + l) * 8);
      f32x16 w = zero16;
      w = __builtin_amdgcn_mfma_f32_32x32x16_bf16(caH0, cbH0, w, 0, 0, 0);
      w = __builtin_amdgcn_mfma_f32_32x32x16_bf16(caH1, cbH1, w, 0, 0, 0);
      w = __builtin_amdgcn_mfma_f32_32x32x16_bf16(caH0, cbL0, w, 0, 0, 0);
      w = __builtin_amdgcn_mfma_f32_32x32x16_bf16(caH1, cbL1, w, 0, 0, 0);
      w = __builtin_amdgcn_mfma_f32_32x32x16_bf16(caL0, cbH0, w, 0, 0, 0);
      w = __builtin_amdgcn_mfma_f32_32x32x16_bf16(caL1, cbH1, w, 0, 0, 0);
      float sb = sqB[colb + j * 32];
      #pragma unroll
      for (int reg = 0; reg < 16; ++reg) {
        int row = rowb + i * 32 + (reg & 3) + 8 * (reg >> 2);
        float l2 = fmaxf(sqA[row] + sb - 2.0f * acc[i][j][reg], 0.f);
        float e = __builtin_amdgcn_exp2f(l2 * nib);   // exp(-L2/(16 bw))
        float kern = e;
        e *= e; kern += e;   // /8
        e *= e; kern += e;   // /4
        e *= e; kern += e;   // /2
        e *= e; kern += e;   // /1
        partial = fmaf(w[reg], kern, partial);
      }
    }
  }
  #pragma unroll
  for (int off = 32; off; off >>= 1) partial += __shfl_xor(partial, off);
  if (l == 0) red[wid] = partial;
  __syncthreads();
  if (tid == 0) {
    float v = (red[0] + red[1] + red[2] + red[3]) * invlen * ((ti == tj) ? 1.0f : 2.0f);
    atomicAdd(out, v);
  }
}

extern "C" void kernel_launch(void* const* d_in, const int* in_sizes, int n_in,
                              void* d_out, int out_size, void* d_ws, size_t ws_size,
                              hipStream_t stream) {
  const float* src = (const float*)d_in[0];
  const float* tgt = (const float*)d_in[1];
  const int* slab  = (const int*)d_in[2];
  const float* tl  = (const float*)d_in[3];
  float* out = (float*)d_out;

  ushort* hiG = (ushort*)d_ws;           // 8192*512 ushorts
  ushort* cH  = hiG + 4194304;           // 8192*32
  ushort* cL  = cH + 262144;
  float* fb   = (float*)(cL + 262144);
  float* sq     = fb;            // 8192 (atomic-accumulated; zeroed below)
  float* m      = fb + 8192;     // 512  (atomic-accumulated; zeroed below)
  float* tsum   = fb + 8704;     // 32
  int*   pres   = (int*)(fb + 8736);  // 32
  float* sval   = fb + 8768;     // 32
  float* tscale = fb + 8800;     // 32
  float* scal   = fb + 8832;     // 2

  hipMemsetAsync(out, 0, sizeof(float), stream);
  hipMemsetAsync(fb, 0, 8864 * sizeof(float), stream);

  hipLaunchKernelGGL(k_split,  dim3(2048), dim3(256), 0, stream, src, tgt, hiG, sq, m);
  hipLaunchKernelGGL(k_tstats, dim3(32),   dim3(256), 0, stream, tl, tsum, pres);
  hipLaunchKernelGGL(k_prep,   dim3(1),    dim3(256), 0, stream, sq, m, slab, tsum, pres, sval, tscale, scal);
  hipLaunchKernelGGL(k_cvec,   dim3(32),   dim3(256), 0, stream, slab, tl, sval, tscale, cH, cL);
  hipLaunchKernelGGL(k_main,   dim3(2080), dim3(256), 0, stream, hiG, cH, cL, sq, scal, out);
}

// Round 8
// 96.459 us; speedup vs baseline: 1.9591x; 1.1360x over previous
//
#include <hip/hip_runtime.h>

#define N_TOT 8192
#define BHALF 4096
#define D 512
#define C 31
#define NKCI 8   // K-chunks of 64
#define QS 21.166666666666668f   // 127/6
#define C2 0.0044644089288178575f // 2*(6/127)^2

typedef float f32x16 __attribute__((ext_vector_type(16)));
typedef int   i32x16 __attribute__((ext_vector_type(16)));
typedef int   i32x4  __attribute__((ext_vector_type(4)));
typedef __bf16 bf16x8 __attribute__((ext_vector_type(8)));

// ---------------- helpers ----------------
__device__ __forceinline__ uint bf16_rne(uint u) {
  return (u + 0x7fffu + ((u >> 16) & 1u)) >> 16;
}
__device__ __forceinline__ void split2(float x, uint& h, uint& lo) {
  uint u = __float_as_uint(x);
  h = bf16_rne(u);
  float hf = __uint_as_float(h << 16);
  lo = bf16_rne(__float_as_uint(x - hf));
}
__device__ __forceinline__ void gll16(const void* g, void* s) {
  __builtin_amdgcn_global_load_lds(
      (const __attribute__((address_space(1))) unsigned int*)g,
      (__attribute__((address_space(3))) unsigned int*)s, 16, 0, 0);
}
__device__ __forceinline__ uint pack4(const float* x, int o) {
  uint r = 0;
  #pragma unroll
  for (int b = 0; b < 4; ++b) {
    float xs = x[o + b] * QS;
    xs = fmaxf(fminf(xs, 127.f), -127.f);
    int q = __float2int_rn(xs);
    r |= (uint)(q & 255) << (8 * b);
  }
  return r;
}

// fused: i8-quantize (fragment-tiled) + row sum-of-squares + column sums
// qG[((rg*16+ksg)*64 + l)*16 + j] = q(x[rg*32+(l&31)][ksg*32+(l>>5)*16+j])
// blocks 0..1023: split (rg = b>>2, kb = b&3, ksg = kb*4+wid)
// blocks 1024..1055: t_label stats
__global__ __launch_bounds__(256) void k_split(const float* __restrict__ src,
                                               const float* __restrict__ tgt,
                                               const float* __restrict__ tl,
                                               uchar* __restrict__ qG,
                                               float* __restrict__ sq,
                                               float* __restrict__ m,
                                               float* __restrict__ tsum,
                                               int* __restrict__ pres) {
  __shared__ float lsq[4][32];
  __shared__ float lcol[128];
  __shared__ float ts[C];
  int tid = threadIdx.x, l = tid & 63, wid = tid >> 6;
  int bx = (int)blockIdx.x;
  if (bx < 1024) {
    int rg = bx >> 2;            // 0..255
    int kb = bx & 3;             // 0..3
    int ksg = kb * 4 + wid;      // 0..15
    int row = rg * 32 + (l & 31);
    int k0 = ksg * 32 + (l >> 5) * 16;
    const float* p = (row < BHALF) ? src + (size_t)row * D : tgt + (size_t)(row - BHALF) * D;
    float x[16];
    #pragma unroll
    for (int q = 0; q < 4; ++q) {
      float4 v = *(const float4*)(p + k0 + q * 4);
      x[q*4+0] = v.x; x[q*4+1] = v.y; x[q*4+2] = v.z; x[q*4+3] = v.w;
    }
    uint4 o = make_uint4(pack4(x, 0), pack4(x, 4), pack4(x, 8), pack4(x, 12));
    *(uint4*)(qG + (((size_t)rg * 16 + ksg) * 64 + l) * 16) = o;
    // row sum-of-squares partial (32 k's of this ksg per row)
    float s = 0.f;
    #pragma unroll
    for (int j = 0; j < 16; ++j) s = fmaf(x[j], x[j], s);
    s += __shfl_xor(s, 32);
    if (l < 32) lsq[wid][l] = s;
    // column partials: butterfly over the 32-row lane bits
    #pragma unroll
    for (int off = 1; off <= 16; off <<= 1)
      #pragma unroll
      for (int j = 0; j < 16; ++j) x[j] += __shfl_xor(x[j], off);
    if ((l & 31) == 0) {
      #pragma unroll
      for (int j = 0; j < 16; ++j) lcol[wid * 32 + (l >> 5) * 16 + j] = x[j];
    }
    __syncthreads();
    if (tid < 32) {
      float t = lsq[0][tid] + lsq[1][tid] + lsq[2][tid] + lsq[3][tid];
      atomicAdd(&sq[rg * 32 + tid], t);
    } else if (tid >= 128) {
      int cc = tid - 128;
      atomicAdd(&m[kb * 128 + cc], lcol[cc]);
    }
  } else {
    int b = bx - 1024;
    if (tid < C) ts[tid] = 0.f;
    __syncthreads();
    int base = b * 128 * C;
    for (int idx = tid; idx < 128 * C; idx += 256) {
      atomicAdd(&ts[idx % C], tl[base + idx]);
    }
    if (tid < 128) {
      int row = b * 128 + tid;
      const float* p = tl + (size_t)row * C;
      float best = p[0]; int bi = 0;
      for (int c = 1; c < C; c++) { float v = p[c]; if (v > best) { best = v; bi = c; } }
      pres[bi] = 1;
    }
    __syncthreads();
    if (tid < C) atomicAdd(&tsum[tid], ts[tid]);
  }
}

// single block: bandwidth scalar + class masks/scales + zero the output
__global__ __launch_bounds__(256) void k_prep(const float* __restrict__ sq,
                                              const float* __restrict__ m,
                                              const int* __restrict__ slab,
                                              const float* __restrict__ tsum,
                                              const int* __restrict__ pres,
                                              float* __restrict__ sval,
                                              float* __restrict__ tscale,
                                              float* __restrict__ scal,
                                              float* __restrict__ out) {
  __shared__ float red[4];
  __shared__ int cnt[C];
  __shared__ float Ssh, Msh;
  int tid = threadIdx.x;
  if (tid < C) cnt[tid] = 0;
  float s = 0.f;
  for (int i = tid; i < N_TOT; i += 256) s += sq[i];
  #pragma unroll
  for (int off = 32; off; off >>= 1) s += __shfl_xor(s, off);
  if ((tid & 63) == 0) red[tid >> 6] = s;
  __syncthreads();
  if (tid == 0) Ssh = red[0] + red[1] + red[2] + red[3];
  __syncthreads();
  float q = 0.f;
  for (int d = tid; d < D; d += 256) q += m[d] * m[d];
  #pragma unroll
  for (int off = 32; off; off >>= 1) q += __shfl_xor(q, off);
  if ((tid & 63) == 0) red[tid >> 6] = q;
  __syncthreads();
  if (tid == 0) Msh = red[0] + red[1] + red[2] + red[3];
  for (int i = tid; i < BHALF; i += 256) atomicAdd(&cnt[slab[i]], 1);
  __syncthreads();
  if (tid == 0) {
    double S = (double)Ssh, M2 = (double)Msh;
    double sumL2 = 2.0 * (double)N_TOT * S - 2.0 * M2;
    double bw = sumL2 / ((double)N_TOT * (double)N_TOT - (double)N_TOT) / 4.0;
    // e = 2^(L2 * scal0) = exp(-L2/(16*bw)); 4 squarings give the other scales
    scal[0] = (float)(-1.4426950408889634 / (16.0 * bw));
    int len = 0;
    for (int c = 0; c < C; c++) {
      int mk = (cnt[c] > 0 && pres[c] != 0) ? 1 : 0;
      len += mk;
      sval[c] = mk ? (1.0f / (float)cnt[c]) : 0.0f;
      float tv = tsum[c];
      tscale[c] = mk ? (1.0f / (tv == 0.0f ? 1.0f : tv)) : 0.0f;
    }
    scal[1] = (len > 0) ? (1.0f / (float)len) : 0.0f;
    out[0] = 0.f;
  }
}

// signed weight vectors -> split hi/lo, fragment-tiled (K=32 classes)
__global__ __launch_bounds__(256) void k_cvec(const int* __restrict__ slab,
                                              const float* __restrict__ tl,
                                              const float* __restrict__ sval,
                                              const float* __restrict__ tscale,
                                              ushort* __restrict__ cH,
                                              ushort* __restrict__ cL) {
  int row = blockIdx.x * 256 + threadIdx.x;
  float c[32];
  if (row < BHALF) {
    int cls = slab[row];
    float v = sval[cls];
    #pragma unroll
    for (int i = 0; i < 32; ++i) c[i] = (i == cls) ? v : 0.f;
  } else {
    const float* p = tl + (size_t)(row - BHALF) * C;
    #pragma unroll
    for (int i = 0; i < C; ++i) c[i] = -p[i] * tscale[i];
    c[C] = 0.f;
  }
  int rg = row >> 5;
  #pragma unroll
  for (int ks = 0; ks < 2; ++ks)
    #pragma unroll
    for (int hf = 0; hf < 2; ++hf) {
      int lane = (row & 31) + (hf << 5);
      size_t base = (((size_t)rg * 2 + ks) * 64 + lane) * 8;
      uint h[8], lo[8];
      #pragma unroll
      for (int j = 0; j < 8; ++j) split2(c[ks * 16 + hf * 8 + j], h[j], lo[j]);
      *(uint2*)(cH + base)     = make_uint2(h[0]|(h[1]<<16),  h[2]|(h[3]<<16));
      *(uint2*)(cH + base + 4) = make_uint2(h[4]|(h[5]<<16),  h[6]|(h[7]<<16));
      *(uint2*)(cL + base)     = make_uint2(lo[0]|(lo[1]<<16), lo[2]|(lo[3]<<16));
      *(uint2*)(cL + base + 4) = make_uint2(lo[4]|(lo[5]<<16), lo[6]|(lo[7]<<16));
    }
}

// main: i8 MFMA distance GEMM (single-buffer BK=64) + folded-exp + 3-plane weight tile
__global__ __launch_bounds__(256, 4) void k_main(
    const uchar* __restrict__ qG,
    const ushort* __restrict__ cH, const ushort* __restrict__ cL,
    const float* __restrict__ sq, const float* __restrict__ scal,
    float* __restrict__ out) {
  __shared__ uint4 As4[1024];  // 16KB: i8 staging uses first 8KB; weight phase all 16KB
  __shared__ uint4 Bs4[1024];
  __shared__ float sqA[128], sqB[128], red[4];
  uchar* As = (uchar*)As4;
  uchar* Bs = (uchar*)Bs4;
  ushort* AsU = (ushort*)As4;
  ushort* BsU = (ushort*)Bs4;

  int tid = threadIdx.x;
  int l = tid & 63, wid = tid >> 6;

  // bijective XCD swizzle (2080 % 8 == 0)
  int bid = (int)blockIdx.x;
  int swz = (bid & 7) * 260 + (bid >> 3);

  // decode upper-triangle tile index
  int ti = 0, rem = swz;
  for (;;) { int w = 64 - ti; if (rem < w) break; rem -= w; ++ti; }
  int tj = ti + rem;

  if (tid < 128) { sqA[tid] = sq[ti * 128 + tid]; sqB[tid] = sq[tj * 128 + tid]; }
  float nib = scal[0], invlen = scal[1];

  i32x16 zeroi;
  f32x16 zero16;
  #pragma unroll
  for (int k = 0; k < 16; ++k) { zeroi[k] = 0; zero16[k] = 0.f; }
  i32x16 acc[2][2];
  acc[0][0] = zeroi; acc[0][1] = zeroi; acc[1][0] = zeroi; acc[1][1] = zeroi;

  int wrg = (wid >> 1) * 2;  // wave's A-side local rg base (compute)
  int wcg = (wid & 1) * 2;   // wave's B-side local rg base (compute)

  // staging role: wid0/1 -> A (rgl {0,1}/{2,3}), wid2/3 -> B
  int rgbase_m = ((wid < 2) ? ti : tj) * 4;
  int rg_off = (wid & 1) * 2;
  uchar* lb_m = (wid < 2) ? As : Bs;

  for (int kci = 0; kci < NKCI; ++kci) {
    #pragma unroll
    for (int r = 0; r < 4; ++r) {
      int rgl = rg_off + (r >> 1), ksl = r & 1;
      const uchar* g = qG + (((size_t)(rgbase_m + rgl) * 16 + kci * 2 + ksl) * 64 + l) * 16;
      gll16(g, lb_m + ((rgl * 2 + ksl) * 64 + l) * 16);
    }
    __syncthreads();
    __builtin_amdgcn_s_setprio(1);
    #pragma unroll
    for (int ksl = 0; ksl < 2; ++ksl) {
      i32x4 a0 = *(const i32x4*)(As + (((wrg + 0) * 2 + ksl) * 64 + l) * 16);
      i32x4 a1 = *(const i32x4*)(As + (((wrg + 1) * 2 + ksl) * 64 + l) * 16);
      i32x4 b0 = *(const i32x4*)(Bs + (((wcg + 0) * 2 + ksl) * 64 + l) * 16);
      i32x4 b1 = *(const i32x4*)(Bs + (((wcg + 1) * 2 + ksl) * 64 + l) * 16);
      acc[0][0] = __builtin_amdgcn_mfma_i32_32x32x32_i8(a0, b0, acc[0][0], 0, 0, 0);
      acc[0][1] = __builtin_amdgcn_mfma_i32_32x32x32_i8(a0, b1, acc[0][1], 0, 0, 0);
      acc[1][0] = __builtin_amdgcn_mfma_i32_32x32x32_i8(a1, b0, acc[1][0], 0, 0, 0);
      acc[1][1] = __builtin_amdgcn_mfma_i32_32x32x32_i8(a1, b1, acc[1][1], 0, 0, 0);
    }
    __builtin_amdgcn_s_setprio(0);
    __syncthreads();
  }

  // stage weight planes: AsU = [caH | caL], BsU = [cbH | cbL] (4096 ushorts each)
  {
    const ushort* gc = (wid & 1) ? cL : cH;
    ushort* lb = ((wid < 2) ? AsU : BsU) + (wid & 1) * 4096;
    int rgbase = ((wid < 2) ? ti : tj) * 4;
    #pragma unroll
    for (int r = 0; r < 8; ++r) {
      int rg = r >> 1, ks = r & 1;
      const ushort* g = gc + (((size_t)(rgbase + rg) * 2 + ks) * 64 + l) * 8;
      gll16(g, lb + ((rg * 2 + ks) * 64 + l) * 8);
    }
  }
  __syncthreads();

  // epilogue: per-quadrant 3-plane weight MFMA, folded-exp gaussian, contraction
  float partial = 0.f;
  int colb = (wid & 1) * 64 + (l & 31);
  int rowb = (wid >> 1) * 64 + 4 * (l >> 5);
  #pragma unroll
  for (int i = 0; i < 2; ++i) {
    bf16x8 caH0 = *(const bf16x8*)(AsU + (((wrg + i) * 2 + 0) * 64 + l) * 8);
    bf16x8 caH1 = *(const bf16x8*)(AsU + (((wrg + i) * 2 + 1) * 64 + l) * 8);
    bf16x8 caL0 = *(const bf16x8*)(AsU + 4096 + (((wrg + i) * 2 + 0) * 64 + l) * 8);
    bf16x8 caL1 = *(const bf16x8*)(AsU + 4096 + (((wrg + i) * 2 + 1) * 64 + l) * 8);
    #pragma unroll
    for (int j = 0; j < 2; ++j) {
      bf16x8 cbH0 = *(const bf16x8*)(BsU + (((wcg + j) * 2 + 0) * 64 + l) * 8);
      bf16x8 cbH1 = *(const bf16x8*)(BsU + (((wcg + j) * 2 + 1) * 64 + l) * 8);
      bf16x8 cbL0 = *(const bf16x8*)(BsU + 4096 + (((wcg + j) * 2 + 0) * 64 + l) * 8);
      bf16x8 cbL1 = *(const bf16x8*)(BsU + 4096 + (((wcg + j) * 2 + 1) * 64 + l) * 8);
      f32x16 w = zero16;
      w = __builtin_amdgcn_mfma_f32_32x32x16_bf16(caH0, cbH0, w, 0, 0, 0);
      w = __builtin_amdgcn_mfma_f32_32x32x16_bf16(caH1, cbH1, w, 0, 0, 0);
      w = __builtin_amdgcn_mfma_f32_32x32x16_bf16(caH0, cbL0, w, 0, 0, 0);
      w = __builtin_amdgcn_mfma_f32_32x32x16_bf16(caH1, cbL1, w, 0, 0, 0);
      w = __builtin_amdgcn_mfma_f32_32x32x16_bf16(caL0, cbH0, w, 0, 0, 0);
      w = __builtin_amdgcn_mfma_f32_32x32x16_bf16(caL1, cbH1, w, 0, 0, 0);
      float sb = sqB[colb + j * 32];
      #pragma unroll
      for (int reg = 0; reg < 16; ++reg) {
        int row = rowb + i * 32 + (reg & 3) + 8 * (reg >> 2);
        float l2 = fmaxf(sqA[row] + sb - C2 * (float)acc[i][j][reg], 0.f);
        float e = __builtin_amdgcn_exp2f(l2 * nib);   // exp(-L2/(16 bw))
        float kern = e;
        e *= e; kern += e;   // /8
        e *= e; kern += e;   // /4
        e *= e; kern += e;   // /2
        e *= e; kern += e;   // /1
        partial = fmaf(w[reg], kern, partial);
      }
    }
  }
  #pragma unroll
  for (int off = 32; off; off >>= 1) partial += __shfl_xor(partial, off);
  if (l == 0) red[wid] = partial;
  __syncthreads();
  if (tid == 0) {
    float v = (red[0] + red[1] + red[2] + red[3]) * invlen * ((ti == tj) ? 1.0f : 2.0f);
    atomicAdd(out, v);
  }
}

extern "C" void kernel_launch(void* const* d_in, const int* in_sizes, int n_in,
                              void* d_out, int out_size, void* d_ws, size_t ws_size,
                              hipStream_t stream) {
  const float* src = (const float*)d_in[0];
  const float* tgt = (const float*)d_in[1];
  const int* slab  = (const int*)d_in[2];
  const float* tl  = (const float*)d_in[3];
  float* out = (float*)d_out;

  uchar*  qG = (uchar*)d_ws;                    // 8192*512 i8 = 4 MB
  ushort* cH = (ushort*)(qG + 4194304);         // 8192*32 ushorts
  ushort* cL = cH + 262144;
  float* fb  = (float*)(cL + 262144);
  float* sq     = fb;            // 8192 (atomic-accumulated; zeroed below)
  float* m      = fb + 8192;     // 512  (atomic-accumulated; zeroed below)
  float* tsum   = fb + 8704;     // 32
  int*   pres   = (int*)(fb + 8736);  // 32
  float* sval   = fb + 8768;     // 32
  float* tscale = fb + 8800;     // 32
  float* scal   = fb + 8832;     // 2

  hipMemsetAsync(fb, 0, 8864 * sizeof(float), stream);
  hipLaunchKernelGGL(k_split, dim3(1056), dim3(256), 0, stream,
                     src, tgt, tl, qG, sq, m, tsum, pres);
  hipLaunchKernelGGL(k_prep,  dim3(1),    dim3(256), 0, stream,
                     sq, m, slab, tsum, pres, sval, tscale, scal, out);
  hipLaunchKernelGGL(k_cvec,  dim3(32),   dim3(256), 0, stream,
                     slab, tl, sval, tscale, cH, cL);
  hipLaunchKernelGGL(k_main,  dim3(2080), dim3(256), 0, stream,
                     qG, cH, cL, sq, scal, out);
}

// Round 9
// 93.763 us; speedup vs baseline: 2.0155x; 1.0288x over previous
//
#include <hip/hip_runtime.h>

#define N_TOT 8192
#define BHALF 4096
#define D 512
#define C 31
#define NKCI 4   // K-chunks of 128
#define QS 21.166666666666668f   // 127/6
#define C2 0.0044644089288178575f // 2*(6/127)^2

typedef float f32x16 __attribute__((ext_vector_type(16)));
typedef int   i32x16 __attribute__((ext_vector_type(16)));
typedef int   i32x4  __attribute__((ext_vector_type(4)));
typedef __bf16 bf16x8 __attribute__((ext_vector_type(8)));

// ---------------- helpers ----------------
__device__ __forceinline__ uint bf16_rne(uint u) {
  return (u + 0x7fffu + ((u >> 16) & 1u)) >> 16;
}
__device__ __forceinline__ void split2(float x, uint& h, uint& lo) {
  uint u = __float_as_uint(x);
  h = bf16_rne(u);
  float hf = __uint_as_float(h << 16);
  lo = bf16_rne(__float_as_uint(x - hf));
}
__device__ __forceinline__ void gll16(const void* g, void* s) {
  __builtin_amdgcn_global_load_lds(
      (const __attribute__((address_space(1))) unsigned int*)g,
      (__attribute__((address_space(3))) unsigned int*)s, 16, 0, 0);
}
__device__ __forceinline__ uint pack4(const float* x, int o) {
  uint r = 0;
  #pragma unroll
  for (int b = 0; b < 4; ++b) {
    float xs = x[o + b] * QS;
    xs = fmaxf(fminf(xs, 127.f), -127.f);
    int q = __float2int_rn(xs);
    r |= (uint)(q & 255) << (8 * b);
  }
  return r;
}

// fused: i8-quantize (fragment-tiled) + row sum-of-squares + column sums
// qG[((rg*16+ksg)*64 + l)*16 + j] = q(x[rg*32+(l&31)][ksg*32+(l>>5)*16+j])
// blocks 0..1023: split (rg = b>>2, kb = b&3, ksg = kb*4+wid)
// blocks 1024..1055: t_label stats
__global__ __launch_bounds__(256) void k_split(const float* __restrict__ src,
                                               const float* __restrict__ tgt,
                                               const float* __restrict__ tl,
                                               uchar* __restrict__ qG,
                                               float* __restrict__ sq,
                                               float* __restrict__ m,
                                               float* __restrict__ tsum,
                                               int* __restrict__ pres) {
  __shared__ float lsq[4][32];
  __shared__ float lcol[128];
  __shared__ float ts[C];
  int tid = threadIdx.x, l = tid & 63, wid = tid >> 6;
  int bx = (int)blockIdx.x;
  if (bx < 1024) {
    int rg = bx >> 2;            // 0..255
    int kb = bx & 3;             // 0..3
    int ksg = kb * 4 + wid;      // 0..15
    int row = rg * 32 + (l & 31);
    int k0 = ksg * 32 + (l >> 5) * 16;
    const float* p = (row < BHALF) ? src + (size_t)row * D : tgt + (size_t)(row - BHALF) * D;
    float x[16];
    #pragma unroll
    for (int q = 0; q < 4; ++q) {
      float4 v = *(const float4*)(p + k0 + q * 4);
      x[q*4+0] = v.x; x[q*4+1] = v.y; x[q*4+2] = v.z; x[q*4+3] = v.w;
    }
    uint4 o = make_uint4(pack4(x, 0), pack4(x, 4), pack4(x, 8), pack4(x, 12));
    *(uint4*)(qG + (((size_t)rg * 16 + ksg) * 64 + l) * 16) = o;
    // row sum-of-squares partial (32 k's of this ksg per row)
    float s = 0.f;
    #pragma unroll
    for (int j = 0; j < 16; ++j) s = fmaf(x[j], x[j], s);
    s += __shfl_xor(s, 32);
    if (l < 32) lsq[wid][l] = s;
    // column partials: butterfly over the 32-row lane bits
    #pragma unroll
    for (int off = 1; off <= 16; off <<= 1)
      #pragma unroll
      for (int j = 0; j < 16; ++j) x[j] += __shfl_xor(x[j], off);
    if ((l & 31) == 0) {
      #pragma unroll
      for (int j = 0; j < 16; ++j) lcol[wid * 32 + (l >> 5) * 16 + j] = x[j];
    }
    __syncthreads();
    if (tid < 32) {
      float t = lsq[0][tid] + lsq[1][tid] + lsq[2][tid] + lsq[3][tid];
      atomicAdd(&sq[rg * 32 + tid], t);
    } else if (tid >= 128) {
      int cc = tid - 128;
      atomicAdd(&m[kb * 128 + cc], lcol[cc]);
    }
  } else {
    int b = bx - 1024;
    if (tid < C) ts[tid] = 0.f;
    __syncthreads();
    int base = b * 128 * C;
    for (int idx = tid; idx < 128 * C; idx += 256) {
      atomicAdd(&ts[idx % C], tl[base + idx]);
    }
    if (tid < 128) {
      int row = b * 128 + tid;
      const float* p = tl + (size_t)row * C;
      float best = p[0]; int bi = 0;
      for (int c = 1; c < C; c++) { float v = p[c]; if (v > best) { best = v; bi = c; } }
      pres[bi] = 1;
    }
    __syncthreads();
    if (tid < C) atomicAdd(&tsum[tid], ts[tid]);
  }
}

// single block: bandwidth scalar + class masks/scales + zero the output
__global__ __launch_bounds__(256) void k_prep(const float* __restrict__ sq,
                                              const float* __restrict__ m,
                                              const int* __restrict__ slab,
                                              const float* __restrict__ tsum,
                                              const int* __restrict__ pres,
                                              float* __restrict__ sval,
                                              float* __restrict__ tscale,
                                              float* __restrict__ scal,
                                              float* __restrict__ out) {
  __shared__ float red[4];
  __shared__ int cnt[C];
  __shared__ float Ssh, Msh;
  int tid = threadIdx.x;
  if (tid < C) cnt[tid] = 0;
  float s = 0.f;
  for (int i = tid; i < N_TOT; i += 256) s += sq[i];
  #pragma unroll
  for (int off = 32; off; off >>= 1) s += __shfl_xor(s, off);
  if ((tid & 63) == 0) red[tid >> 6] = s;
  __syncthreads();
  if (tid == 0) Ssh = red[0] + red[1] + red[2] + red[3];
  __syncthreads();
  float q = 0.f;
  for (int d = tid; d < D; d += 256) q += m[d] * m[d];
  #pragma unroll
  for (int off = 32; off; off >>= 1) q += __shfl_xor(q, off);
  if ((tid & 63) == 0) red[tid >> 6] = q;
  __syncthreads();
  if (tid == 0) Msh = red[0] + red[1] + red[2] + red[3];
  for (int i = tid; i < BHALF; i += 256) atomicAdd(&cnt[slab[i]], 1);
  __syncthreads();
  if (tid == 0) {
    double S = (double)Ssh, M2 = (double)Msh;
    double sumL2 = 2.0 * (double)N_TOT * S - 2.0 * M2;
    double bw = sumL2 / ((double)N_TOT * (double)N_TOT - (double)N_TOT) / 4.0;
    // e = 2^(L2 * scal0) = exp(-L2/(16*bw)); 4 squarings give the other scales
    scal[0] = (float)(-1.4426950408889634 / (16.0 * bw));
    int len = 0;
    for (int c = 0; c < C; c++) {
      int mk = (cnt[c] > 0 && pres[c] != 0) ? 1 : 0;
      len += mk;
      sval[c] = mk ? (1.0f / (float)cnt[c]) : 0.0f;
      float tv = tsum[c];
      tscale[c] = mk ? (1.0f / (tv == 0.0f ? 1.0f : tv)) : 0.0f;
    }
    scal[1] = (len > 0) ? (1.0f / (float)len) : 0.0f;
    out[0] = 0.f;
  }
}

// main: i8 MFMA distance GEMM (single-buffer BK=128, 4 phases) + folded-exp
// + inline weight-fragment construction + 3-plane weight tile
__global__ __launch_bounds__(256, 4) void k_main(
    const uchar* __restrict__ qG,
    const int* __restrict__ slab, const float* __restrict__ tl,
    const float* __restrict__ sval, const float* __restrict__ tscale,
    const float* __restrict__ sq, const float* __restrict__ scal,
    float* __restrict__ out) {
  __shared__ uint4 As4[1024];  // 16KB: i8 tile 128x128 in k-loop; weight planes after
  __shared__ uint4 Bs4[1024];
  __shared__ float sqA[128], sqB[128], red[4];
  uchar* As = (uchar*)As4;
  uchar* Bs = (uchar*)Bs4;
  ushort* AsU = (ushort*)As4;
  ushort* BsU = (ushort*)Bs4;

  int tid = threadIdx.x;
  int l = tid & 63, wid = tid >> 6;

  // bijective XCD swizzle (2080 % 8 == 0)
  int bid = (int)blockIdx.x;
  int swz = (bid & 7) * 260 + (bid >> 3);

  // decode upper-triangle tile index
  int ti = 0, rem = swz;
  for (;;) { int w = 64 - ti; if (rem < w) break; rem -= w; ++ti; }
  int tj = ti + rem;

  if (tid < 128) { sqA[tid] = sq[ti * 128 + tid]; sqB[tid] = sq[tj * 128 + tid]; }
  float nib = scal[0], invlen = scal[1];

  i32x16 zeroi;
  f32x16 zero16;
  #pragma unroll
  for (int k = 0; k < 16; ++k) { zeroi[k] = 0; zero16[k] = 0.f; }
  i32x16 acc[2][2];
  acc[0][0] = zeroi; acc[0][1] = zeroi; acc[1][0] = zeroi; acc[1][1] = zeroi;

  int wrg = (wid >> 1) * 2;  // wave's A-side local rg base (compute)
  int wcg = (wid & 1) * 2;   // wave's B-side local rg base (compute)

  // staging role: wid0/1 -> A (rgl {0,1}/{2,3}), wid2/3 -> B
  int rgbase_m = ((wid < 2) ? ti : tj) * 4;
  int rg_off = (wid & 1) * 2;
  uchar* lb_m = (wid < 2) ? As : Bs;

  for (int kci = 0; kci < NKCI; ++kci) {
    #pragma unroll
    for (int r = 0; r < 8; ++r) {
      int rgl = rg_off + (r >> 2), ksl = r & 3;
      const uchar* g = qG + (((size_t)(rgbase_m + rgl) * 16 + kci * 4 + ksl) * 64 + l) * 16;
      gll16(g, lb_m + ((rgl * 4 + ksl) * 64 + l) * 16);
    }
    __syncthreads();
    __builtin_amdgcn_s_setprio(1);
    #pragma unroll
    for (int ksl = 0; ksl < 4; ++ksl) {
      i32x4 a0 = *(const i32x4*)(As + (((wrg + 0) * 4 + ksl) * 64 + l) * 16);
      i32x4 a1 = *(const i32x4*)(As + (((wrg + 1) * 4 + ksl) * 64 + l) * 16);
      i32x4 b0 = *(const i32x4*)(Bs + (((wcg + 0) * 4 + ksl) * 64 + l) * 16);
      i32x4 b1 = *(const i32x4*)(Bs + (((wcg + 1) * 4 + ksl) * 64 + l) * 16);
      acc[0][0] = __builtin_amdgcn_mfma_i32_32x32x32_i8(a0, b0, acc[0][0], 0, 0, 0);
      acc[0][1] = __builtin_amdgcn_mfma_i32_32x32x32_i8(a0, b1, acc[0][1], 0, 0, 0);
      acc[1][0] = __builtin_amdgcn_mfma_i32_32x32x32_i8(a1, b0, acc[1][0], 0, 0, 0);
      acc[1][1] = __builtin_amdgcn_mfma_i32_32x32x32_i8(a1, b1, acc[1][1], 0, 0, 0);
    }
    __builtin_amdgcn_s_setprio(0);
    __syncthreads();
  }

  // inline weight-fragment construction (replaces k_cvec + staging):
  // 16 planes (side 0/1 x rgl 0..3 x ks 0/1) x 64 lanes; 4 iterations of 256 threads.
  // plane layout written == what the weight MFMAs read: [(rgl*2+ks)*64+l]*8 ushorts (hi),
  // +4096 (lo), in AsU (side 0) / BsU (side 1).
  #pragma unroll
  for (int it = 0; it < 4; ++it) {
    int slot = tid + it * 256;
    int pl = slot >> 6;             // 0..15
    int ll = slot & 63;
    int side = pl >> 3;             // 0=A, 1=B
    int rgl = (pl & 7) >> 1;        // 0..3
    int ks = pl & 1;                // 0..1
    int row = (side ? tj : ti) * 128 + rgl * 32 + (ll & 31);
    int j0 = ks * 16 + (ll >> 5) * 8;
    float vals[8];
    if (row < BHALF) {
      int cls = slab[row];
      float v = sval[cls];
      #pragma unroll
      for (int jj = 0; jj < 8; ++jj) vals[jj] = (j0 + jj == cls) ? v : 0.f;
    } else {
      const float* p = tl + (size_t)(row - BHALF) * C;
      #pragma unroll
      for (int jj = 0; jj < 8; ++jj) {
        int cj = j0 + jj;
        vals[jj] = (cj < C) ? -p[cj] * tscale[cj] : 0.f;
      }
    }
    uint h[8], lo[8];
    #pragma unroll
    for (int jj = 0; jj < 8; ++jj) split2(vals[jj], h[jj], lo[jj]);
    ushort* base = (side ? BsU : AsU) + ((rgl * 2 + ks) * 64 + ll) * 8;
    *(uint4*)base = make_uint4(h[0]|(h[1]<<16), h[2]|(h[3]<<16),
                               h[4]|(h[5]<<16), h[6]|(h[7]<<16));
    *(uint4*)(base + 4096) = make_uint4(lo[0]|(lo[1]<<16), lo[2]|(lo[3]<<16),
                                        lo[4]|(lo[5]<<16), lo[6]|(lo[7]<<16));
  }
  __syncthreads();

  // epilogue: per-quadrant 3-plane weight MFMA, folded-exp gaussian, contraction
  float partial = 0.f;
  int colb = (wid & 1) * 64 + (l & 31);
  int rowb = (wid >> 1) * 64 + 4 * (l >> 5);
  #pragma unroll
  for (int i = 0; i < 2; ++i) {
    bf16x8 caH0 = *(const bf16x8*)(AsU + (((wrg + i) * 2 + 0) * 64 + l) * 8);
    bf16x8 caH1 = *(const bf16x8*)(AsU + (((wrg + i) * 2 + 1) * 64 + l) * 8);
    bf16x8 caL0 = *(const bf16x8*)(AsU + 4096 + (((wrg + i) * 2 + 0) * 64 + l) * 8);
    bf16x8 caL1 = *(const bf16x8*)(AsU + 4096 + (((wrg + i) * 2 + 1) * 64 + l) * 8);
    #pragma unroll
    for (int j = 0; j < 2; ++j) {
      bf16x8 cbH0 = *(const bf16x8*)(BsU + (((wcg + j) * 2 + 0) * 64 + l) * 8);
      bf16x8 cbH1 = *(const bf16x8*)(BsU + (((wcg + j) * 2 + 1) * 64 + l) * 8);
      bf16x8 cbL0 = *(const bf16x8*)(BsU + 4096 + (((wcg + j) * 2 + 0) * 64 + l) * 8);
      bf16x8 cbL1 = *(const bf16x8*)(BsU + 4096 + (((wcg + j) * 2 + 1) * 64 + l) * 8);
      f32x16 w = zero16;
      w = __builtin_amdgcn_mfma_f32_32x32x16_bf16(caH0, cbH0, w, 0, 0, 0);
      w = __builtin_amdgcn_mfma_f32_32x32x16_bf16(caH1, cbH1, w, 0, 0, 0);
      w = __builtin_amdgcn_mfma_f32_32x32x16_bf16(caH0, cbL0, w, 0, 0, 0);
      w = __builtin_amdgcn_mfma_f32_32x32x16_bf16(caH1, cbL1, w, 0, 0, 0);
      w = __builtin_amdgcn_mfma_f32_32x32x16_bf16(caL0, cbH0, w, 0, 0, 0);
      w = __builtin_amdgcn_mfma_f32_32x32x16_bf16(caL1, cbH1, w, 0, 0, 0);
      float sb = sqB[colb + j * 32];
      #pragma unroll
      for (int reg = 0; reg < 16; ++reg) {
        int row = rowb + i * 32 + (reg & 3) + 8 * (reg >> 2);
        float l2 = fmaxf(sqA[row] + sb - C2 * (float)acc[i][j][reg], 0.f);
        float e = __builtin_amdgcn_exp2f(l2 * nib);   // exp(-L2/(16 bw))
        float kern = e;
        e *= e; kern += e;   // /8
        e *= e; kern += e;   // /4
        e *= e; kern += e;   // /2
        e *= e; kern += e;   // /1
        partial = fmaf(w[reg], kern, partial);
      }
    }
  }
  #pragma unroll
  for (int off = 32; off; off >>= 1) partial += __shfl_xor(partial, off);
  if (l == 0) red[wid] = partial;
  __syncthreads();
  if (tid == 0) {
    float v = (red[0] + red[1] + red[2] + red[3]) * invlen * ((ti == tj) ? 1.0f : 2.0f);
    atomicAdd(out, v);
  }
}

extern "C" void kernel_launch(void* const* d_in, const int* in_sizes, int n_in,
                              void* d_out, int out_size, void* d_ws, size_t ws_size,
                              hipStream_t stream) {
  const float* src = (const float*)d_in[0];
  const float* tgt = (const float*)d_in[1];
  const int* slab  = (const int*)d_in[2];
  const float* tl  = (const float*)d_in[3];
  float* out = (float*)d_out;

  uchar*  qG = (uchar*)d_ws;                    // 8192*512 i8 = 4 MB
  float* fb  = (float*)(qG + 4194304);
  float* sq     = fb;            // 8192 (atomic-accumulated; zeroed below)
  float* m      = fb + 8192;     // 512  (atomic-accumulated; zeroed below)
  float* tsum   = fb + 8704;     // 32
  int*   pres   = (int*)(fb + 8736);  // 32
  float* sval   = fb + 8768;     // 32
  float* tscale = fb + 8800;     // 32
  float* scal   = fb + 8832;     // 2

  hipMemsetAsync(fb, 0, 8864 * sizeof(float), stream);
  hipLaunchKernelGGL(k_split, dim3(1056), dim3(256), 0, stream,
                     src, tgt, tl, qG, sq, m, tsum, pres);
  hipLaunchKernelGGL(k_prep,  dim3(1),    dim3(256), 0, stream,
                     sq, m, slab, tsum, pres, sval, tscale, scal, out);
  hipLaunchKernelGGL(k_main,  dim3(2080), dim3(256), 0, stream,
                     qG, slab, tl, sval, tscale, sq, scal, out);
}

// Round 10
// 89.362 us; speedup vs baseline: 2.1147x; 1.0492x over previous
//
#include <hip/hip_runtime.h>

#define N_TOT 8192
#define BHALF 4096
#define D 512
#define C 31
#define QS 21.166666666666668f    // 127/6
#define C2 0.0044644089288178575f // 2*(6/127)^2

typedef float f32x16 __attribute__((ext_vector_type(16)));
typedef int   i32x16 __attribute__((ext_vector_type(16)));
typedef int   i32x4  __attribute__((ext_vector_type(4)));
typedef __bf16 bf16x8 __attribute__((ext_vector_type(8)));

// ---------------- helpers ----------------
__device__ __forceinline__ uint bf16_rne(uint u) {
  return (u + 0x7fffu + ((u >> 16) & 1u)) >> 16;
}
__device__ __forceinline__ void split2(float x, uint& h, uint& lo) {
  uint u = __float_as_uint(x);
  h = bf16_rne(u);
  float hf = __uint_as_float(h << 16);
  lo = bf16_rne(__float_as_uint(x - hf));
}
__device__ __forceinline__ void gll16(const void* g, void* s) {
  __builtin_amdgcn_global_load_lds(
      (const __attribute__((address_space(1))) unsigned int*)g,
      (__attribute__((address_space(3))) unsigned int*)s, 16, 0, 0);
}
__device__ __forceinline__ uint pack4(const float* x, int o) {
  uint r = 0;
  #pragma unroll
  for (int b = 0; b < 4; ++b) {
    float xs = x[o + b] * QS;
    xs = fmaxf(fminf(xs, 127.f), -127.f);
    int q = __float2int_rn(xs);
    r |= (uint)(q & 255) << (8 * b);
  }
  return r;
}

// fused: i8-quantize (fragment-tiled) + row sq + col sums; blocks>=1024: t-stats + slab hist
__global__ __launch_bounds__(256) void k_split(const float* __restrict__ src,
                                               const float* __restrict__ tgt,
                                               const float* __restrict__ tl,
                                               const int* __restrict__ slab,
                                               uchar* __restrict__ qG,
                                               float* __restrict__ sq,
                                               float* __restrict__ m,
                                               float* __restrict__ tsum,
                                               int* __restrict__ pres,
                                               int* __restrict__ cnt,
                                               float* __restrict__ out) {
  __shared__ float lsq[4][32];
  __shared__ float lcol[128];
  __shared__ float ts[C];
  __shared__ int hcnt[C];
  int tid = threadIdx.x, l = tid & 63, wid = tid >> 6;
  int bx = (int)blockIdx.x;
  if (bx < 1024) {
    int rg = bx >> 2;            // 0..255
    int kb = bx & 3;             // 0..3
    int ksg = kb * 4 + wid;      // 0..15
    int row = rg * 32 + (l & 31);
    int k0 = ksg * 32 + (l >> 5) * 16;
    const float* p = (row < BHALF) ? src + (size_t)row * D : tgt + (size_t)(row - BHALF) * D;
    float x[16];
    #pragma unroll
    for (int q = 0; q < 4; ++q) {
      float4 v = *(const float4*)(p + k0 + q * 4);
      x[q*4+0] = v.x; x[q*4+1] = v.y; x[q*4+2] = v.z; x[q*4+3] = v.w;
    }
    uint4 o = make_uint4(pack4(x, 0), pack4(x, 4), pack4(x, 8), pack4(x, 12));
    *(uint4*)(qG + (((size_t)rg * 16 + ksg) * 64 + l) * 16) = o;
    float s = 0.f;
    #pragma unroll
    for (int j = 0; j < 16; ++j) s = fmaf(x[j], x[j], s);
    s += __shfl_xor(s, 32);
    if (l < 32) lsq[wid][l] = s;
    #pragma unroll
    for (int off = 1; off <= 16; off <<= 1)
      #pragma unroll
      for (int j = 0; j < 16; ++j) x[j] += __shfl_xor(x[j], off);
    if ((l & 31) == 0) {
      #pragma unroll
      for (int j = 0; j < 16; ++j) lcol[wid * 32 + (l >> 5) * 16 + j] = x[j];
    }
    __syncthreads();
    if (tid < 32) {
      float t = lsq[0][tid] + lsq[1][tid] + lsq[2][tid] + lsq[3][tid];
      atomicAdd(&sq[rg * 32 + tid], t);
    } else if (tid >= 128) {
      int cc = tid - 128;
      atomicAdd(&m[kb * 128 + cc], lcol[cc]);
    }
  } else {
    int b = bx - 1024;  // 0..31
    if (tid < C) { ts[tid] = 0.f; hcnt[tid] = 0; }
    __syncthreads();
    int base = b * 128 * C;
    for (int idx = tid; idx < 128 * C; idx += 256) {
      atomicAdd(&ts[idx % C], tl[base + idx]);
    }
    if (tid < 128) {
      int row = b * 128 + tid;
      const float* p = tl + (size_t)row * C;
      float best = p[0]; int bi = 0;
      for (int c = 1; c < C; c++) { float v = p[c]; if (v > best) { best = v; bi = c; } }
      pres[bi] = 1;
      atomicAdd(&hcnt[slab[row]], 1);
    }
    if (b == 0 && tid == 255) out[0] = 0.f;
    __syncthreads();
    if (tid < C) {
      atomicAdd(&tsum[tid], ts[tid]);
      atomicAdd(&cnt[tid], hcnt[tid]);
    }
  }
}

#define WAITV4 asm volatile("s_waitcnt vmcnt(4)" ::: "memory")
#define WAITV0 asm volatile("s_waitcnt vmcnt(0)" ::: "memory")
#define WAITL0 asm volatile("s_waitcnt lgkmcnt(0)" ::: "memory")

// main: i8 MFMA GEMM, 2-buffer BK=64, counted-vmcnt pipeline + inline prep + weight tile
__global__ __launch_bounds__(256, 4) void k_main(
    const uchar* __restrict__ qG,
    const int* __restrict__ slab, const float* __restrict__ tl,
    const float* __restrict__ sq, const float* __restrict__ m,
    const float* __restrict__ tsum, const int* __restrict__ pres,
    const int* __restrict__ cnt, float* __restrict__ out) {
  __shared__ uint4 lds4[2][1024];  // 2 x 16KB: [A 8KB | B 8KB] per buffer
  __shared__ float sqA[128], sqB[128], red[8];
  __shared__ float svalS[32], tscaleS[32], scalS[1];

  int tid = threadIdx.x;
  int l = tid & 63, wid = tid >> 6;

  // bijective XCD swizzle (2080 % 8 == 0)
  int bid = (int)blockIdx.x;
  int swz = (bid & 7) * 260 + (bid >> 3);
  int ti = 0, rem = swz;
  for (;;) { int w = 64 - ti; if (rem < w) break; rem -= w; ++ti; }
  int tj = ti + rem;

  i32x16 zeroi;
  f32x16 zero16;
  #pragma unroll
  for (int k = 0; k < 16; ++k) { zeroi[k] = 0; zero16[k] = 0.f; }
  i32x16 acc[2][2];
  acc[0][0] = zeroi; acc[0][1] = zeroi; acc[1][0] = zeroi; acc[1][1] = zeroi;

  int wrg = (wid >> 1) * 2;  // wave's A-side compute rg base
  int wcg = (wid & 1) * 2;   // wave's B-side compute rg base

  // staging role: wid0/1 -> A halves, wid2/3 -> B halves
  int rgbase_m = ((wid < 2) ? ti : tj) * 4;
  int rg_off = (wid & 1) * 2;
  int side_off = (wid < 2) ? 0 : 8192;

#define STAGE(P) do {                                                              \
    uchar* lb = ((uchar*)lds4[(P) & 1]) + side_off;                                \
    _Pragma("unroll")                                                              \
    for (int r = 0; r < 4; ++r) {                                                  \
      int rgl = rg_off + (r >> 1), ksl = r & 1;                                    \
      const uchar* g = qG + (((size_t)(rgbase_m + rgl) * 16 + ((P) * 2 + ksl)) * 64 + l) * 16; \
      gll16(g, lb + ((rgl * 2 + ksl) * 64 + l) * 16);                              \
    }                                                                              \
  } while (0)

  STAGE(0);
  #pragma unroll
  for (int p = 0; p < 8; ++p) {
    if (p + 1 < 8) STAGE(p + 1);
    if (p < 7) { WAITV4; } else { WAITV0; }
    __builtin_amdgcn_sched_barrier(0);
    __builtin_amdgcn_s_barrier();
    uchar* As = (uchar*)lds4[p & 1];
    uchar* Bs = As + 8192;
    __builtin_amdgcn_s_setprio(1);
    #pragma unroll
    for (int ksl = 0; ksl < 2; ++ksl) {
      i32x4 a0 = *(const i32x4*)(As + (((wrg + 0) * 2 + ksl) * 64 + l) * 16);
      i32x4 a1 = *(const i32x4*)(As + (((wrg + 1) * 2 + ksl) * 64 + l) * 16);
      i32x4 b0 = *(const i32x4*)(Bs + (((wcg + 0) * 2 + ksl) * 64 + l) * 16);
      i32x4 b1 = *(const i32x4*)(Bs + (((wcg + 1) * 2 + ksl) * 64 + l) * 16);
      acc[0][0] = __builtin_amdgcn_mfma_i32_32x32x32_i8(a0, b0, acc[0][0], 0, 0, 0);
      acc[0][1] = __builtin_amdgcn_mfma_i32_32x32x32_i8(a0, b1, acc[0][1], 0, 0, 0);
      acc[1][0] = __builtin_amdgcn_mfma_i32_32x32x32_i8(a1, b0, acc[1][0], 0, 0, 0);
      acc[1][1] = __builtin_amdgcn_mfma_i32_32x32x32_i8(a1, b1, acc[1][1], 0, 0, 0);
    }
    __builtin_amdgcn_s_setprio(0);
    WAITL0;                              // no wave signals the closing barrier with
    __builtin_amdgcn_sched_barrier(0);   // pending ds_reads of this buffer (rule #18)
    __builtin_amdgcn_s_barrier();
  }
#undef STAGE

  // ---- redundant per-block prep (replaces k_prep dispatch) ----
  if (tid < 128) { sqA[tid] = sq[ti * 128 + tid]; sqB[tid] = sq[tj * 128 + tid]; }
  float s = 0.f;
  for (int i = tid; i < N_TOT; i += 256) s += sq[i];
  float q = 0.f;
  for (int d = tid; d < D; d += 256) q += m[d] * m[d];
  #pragma unroll
  for (int off = 32; off; off >>= 1) { s += __shfl_xor(s, off); q += __shfl_xor(q, off); }
  if (l == 0) { red[wid] = s; red[4 + wid] = q; }
  __syncthreads();
  float Ssum = red[0] + red[1] + red[2] + red[3];
  float Msum = red[4] + red[5] + red[6] + red[7];
  double sumL2 = 2.0 * (double)N_TOT * (double)Ssum - 2.0 * (double)Msum;
  double bw = sumL2 / ((double)N_TOT * (double)N_TOT - (double)N_TOT) / 4.0;
  float nib = (float)(-1.4426950408889634 / (16.0 * bw));  // e = 2^(L2*nib)
  if (tid < 32) {
    int c = tid;
    int cc = 0; float tv = 0.f; int pr = 0;
    if (c < C) { cc = cnt[c]; tv = tsum[c]; pr = pres[c]; }
    int mk = (cc > 0 && pr != 0) ? 1 : 0;
    unsigned long long ball = __ballot(mk);
    int len = __popcll(ball);
    svalS[c] = mk ? (1.0f / (float)cc) : 0.f;
    tscaleS[c] = mk ? (1.0f / (tv == 0.f ? 1.f : tv)) : 0.f;
    if (c == 0) scalS[0] = (len > 0) ? (1.0f / (float)len) : 0.f;
  }
  __syncthreads();

  // ---- inline weight-fragment construction into buf0 (A planes) / buf1 (B planes) ----
  ushort* AsU = (ushort*)lds4[0];
  ushort* BsU = (ushort*)lds4[1];
  #pragma unroll
  for (int it = 0; it < 4; ++it) {
    int slot = tid + it * 256;
    int pl = slot >> 6;             // 0..15
    int ll = slot & 63;
    int side = pl >> 3;             // 0=A, 1=B
    int rgl = (pl & 7) >> 1;        // 0..3
    int ks = pl & 1;                // 0..1
    int row = (side ? tj : ti) * 128 + rgl * 32 + (ll & 31);
    int j0 = ks * 16 + (ll >> 5) * 8;
    float vals[8];
    if (row < BHALF) {
      int cls = slab[row];
      float v = svalS[cls];
      #pragma unroll
      for (int jj = 0; jj < 8; ++jj) vals[jj] = (j0 + jj == cls) ? v : 0.f;
    } else {
      const float* p = tl + (size_t)(row - BHALF) * C;
      #pragma unroll
      for (int jj = 0; jj < 8; ++jj) {
        int cj = j0 + jj;
        vals[jj] = (cj < C) ? -p[cj] * tscaleS[cj] : 0.f;
      }
    }
    uint h[8], lo[8];
    #pragma unroll
    for (int jj = 0; jj < 8; ++jj) split2(vals[jj], h[jj], lo[jj]);
    ushort* base = (side ? BsU : AsU) + ((rgl * 2 + ks) * 64 + ll) * 8;
    *(uint4*)base = make_uint4(h[0]|(h[1]<<16), h[2]|(h[3]<<16),
                               h[4]|(h[5]<<16), h[6]|(h[7]<<16));
    *(uint4*)(base + 4096) = make_uint4(lo[0]|(lo[1]<<16), lo[2]|(lo[3]<<16),
                                        lo[4]|(lo[5]<<16), lo[6]|(lo[7]<<16));
  }
  __syncthreads();

  // ---- epilogue: 3-plane weight MFMA, folded-exp gaussian, contraction ----
  float partial = 0.f;
  int colb = (wid & 1) * 64 + (l & 31);
  int rowb = (wid >> 1) * 64 + 4 * (l >> 5);
  #pragma unroll
  for (int i = 0; i < 2; ++i) {
    bf16x8 caH0 = *(const bf16x8*)(AsU + (((wrg + i) * 2 + 0) * 64 + l) * 8);
    bf16x8 caH1 = *(const bf16x8*)(AsU + (((wrg + i) * 2 + 1) * 64 + l) * 8);
    bf16x8 caL0 = *(const bf16x8*)(AsU + 4096 + (((wrg + i) * 2 + 0) * 64 + l) * 8);
    bf16x8 caL1 = *(const bf16x8*)(AsU + 4096 + (((wrg + i) * 2 + 1) * 64 + l) * 8);
    #pragma unroll
    for (int j = 0; j < 2; ++j) {
      bf16x8 cbH0 = *(const bf16x8*)(BsU + (((wcg + j) * 2 + 0) * 64 + l) * 8);
      bf16x8 cbH1 = *(const bf16x8*)(BsU + (((wcg + j) * 2 + 1) * 64 + l) * 8);
      bf16x8 cbL0 = *(const bf16x8*)(BsU + 4096 + (((wcg + j) * 2 + 0) * 64 + l) * 8);
      bf16x8 cbL1 = *(const bf16x8*)(BsU + 4096 + (((wcg + j) * 2 + 1) * 64 + l) * 8);
      f32x16 w = zero16;
      w = __builtin_amdgcn_mfma_f32_32x32x16_bf16(caH0, cbH0, w, 0, 0, 0);
      w = __builtin_amdgcn_mfma_f32_32x32x16_bf16(caH1, cbH1, w, 0, 0, 0);
      w = __builtin_amdgcn_mfma_f32_32x32x16_bf16(caH0, cbL0, w, 0, 0, 0);
      w = __builtin_amdgcn_mfma_f32_32x32x16_bf16(caH1, cbL1, w, 0, 0, 0);
      w = __builtin_amdgcn_mfma_f32_32x32x16_bf16(caL0, cbH0, w, 0, 0, 0);
      w = __builtin_amdgcn_mfma_f32_32x32x16_bf16(caL1, cbH1, w, 0, 0, 0);
      float sb = sqB[colb + j * 32];
      #pragma unroll
      for (int reg = 0; reg < 16; ++reg) {
        int row = rowb + i * 32 + (reg & 3) + 8 * (reg >> 2);
        float l2 = fmaxf(sqA[row] + sb - C2 * (float)acc[i][j][reg], 0.f);
        float e = __builtin_amdgcn_exp2f(l2 * nib);
        float kern = e;
        e *= e; kern += e;
        e *= e; kern += e;
        e *= e; kern += e;
        e *= e; kern += e;
        partial = fmaf(w[reg], kern, partial);
      }
    }
  }
  #pragma unroll
  for (int off = 32; off; off >>= 1) partial += __shfl_xor(partial, off);
  if (l == 0) red[wid] = partial;
  __syncthreads();
  if (tid == 0) {
    float v = (red[0] + red[1] + red[2] + red[3]) * scalS[0] * ((ti == tj) ? 1.0f : 2.0f);
    atomicAdd(out, v);
  }
}

extern "C" void kernel_launch(void* const* d_in, const int* in_sizes, int n_in,
                              void* d_out, int out_size, void* d_ws, size_t ws_size,
                              hipStream_t stream) {
  const float* src = (const float*)d_in[0];
  const float* tgt = (const float*)d_in[1];
  const int* slab  = (const int*)d_in[2];
  const float* tl  = (const float*)d_in[3];
  float* out = (float*)d_out;

  uchar*  qG = (uchar*)d_ws;                    // 8192*512 i8 = 4 MB
  float* fb  = (float*)(qG + 4194304);
  float* sq   = fb;                  // 8192
  float* m    = fb + 8192;           // 512
  float* tsum = fb + 8704;           // 32
  int*   pres = (int*)(fb + 8736);   // 32
  int*   cnt  = (int*)(fb + 8768);   // 32

  hipMemsetAsync(fb, 0, 8800 * sizeof(float), stream);
  hipLaunchKernelGGL(k_split, dim3(1056), dim3(256), 0, stream,
                     src, tgt, tl, slab, qG, sq, m, tsum, pres, cnt, out);
  hipLaunchKernelGGL(k_main,  dim3(2080), dim3(256), 0, stream,
                     qG, slab, tl, sq, m, tsum, pres, cnt, out);
}